// Round 10
// baseline (462.732 us; speedup 1.0000x reference)
//
#include <hip/hip_runtime.h>
#include <stdint.h>

#define B_ 2
#define E_ 8
#define N_ 1024
#define D_ 1024
#define H_ 4096

typedef float f32x4 __attribute__((ext_vector_type(4)));
typedef __bf16 bf16x8 __attribute__((ext_vector_type(8)));
typedef __attribute__((address_space(3))) const unsigned short lds_cus;

__device__ __forceinline__ unsigned short f2bf(float f) {
  union { float f; uint32_t u; } v; v.f = f;
  uint32_t u = v.u;
  return (unsigned short)((u + 0x7FFFu + ((u >> 16) & 1u)) >> 16);  // RNE
}

// tanh-form GELU (max |delta| vs exact erf-GELU ~1e-3, inside threshold headroom)
__device__ __forceinline__ float gelu_fast(float x) {
  float x3 = x * x * x;
  float y = 0.79788456080286536f * (x + 0.044715f * x3);
  float e = __expf(2.0f * y);
  float t = 1.0f - 2.0f / (e + 1.0f);   // tanh(y)
  return 0.5f * x * (1.0f + t);
}

__device__ __forceinline__ void gload_lds16(const unsigned short* g, unsigned short* l) {
  __builtin_amdgcn_global_load_lds(
      (__attribute__((address_space(1))) void*)g,
      (__attribute__((address_space(3))) void*)l,
      16, 0, 0);
}

__device__ __forceinline__ bf16x8 lds_read_b128(lds_cus* p) {
  bf16x8 r;
  asm volatile("ds_read_b128 %0, %1" : "=v"(r) : "v"(p));
  return r;
}

// ---- elementwise fp32 -> bf16 convert (x) ----
__global__ void cvt_x_kernel(const float* __restrict__ in, unsigned short* __restrict__ out, int n4) {
  int idx = blockIdx.x * blockDim.x + threadIdx.x;
  int stride = gridDim.x * blockDim.x;
  const float4* in4 = (const float4*)in;
  ushort4* out4 = (ushort4*)out;
  for (int i = idx; i < n4; i += stride) {
    float4 f = in4[i];
    ushort4 o;
    o.x = f2bf(f.x); o.y = f2bf(f.y); o.z = f2bf(f.z); o.w = f2bf(f.w);
    out4[i] = o;
  }
}

// ---- tiled transpose + convert: in fp32 [R][C] per expert -> out bf16 [C][R] ----
__global__ void transpose_cvt_kernel(const float* __restrict__ in, unsigned short* __restrict__ out,
                                     int R, int C) {
  __shared__ float tile[32][33];
  const size_t eoff = (size_t)blockIdx.z * R * C;
  const float* src = in + eoff;
  unsigned short* dst = out + eoff;
  const int c0 = blockIdx.x * 32, r0 = blockIdx.y * 32;
  const int tx = threadIdx.x, ty = threadIdx.y;
#pragma unroll
  for (int i = 0; i < 4; ++i)
    tile[ty + 8 * i][tx] = src[(size_t)(r0 + ty + 8 * i) * C + c0 + tx];
  __syncthreads();
#pragma unroll
  for (int i = 0; i < 4; ++i)
    dst[(size_t)(c0 + ty + 8 * i) * R + r0 + tx] = f2bf(tile[tx][ty + 8 * i]);
}

// ============================================================================
// GEMM1 (R10): 128x128 tile, BK=64, 4 waves (2x2), dbuf, 64KB LDS ->
// 2 blocks/CU co-residency so per-block HBM store-drains overlap the other
// block's K-loop (in-order vmcnt retirement serializes drains at 1 block/CU).
// Fully counted schedule: per K-tile 2 phases, each {8 asm ds_read | 2 STAGE
// into the other buffer | lgkm(0)+sched_barrier | 16 MFMA | vmcnt(4) |
// barrier}. vmcnt(4) mid-tile retires k1(t) (oldest 4); at boundary retires
// k0(t+1). Tail uses vmcnt(0). T2 slot-XOR swizzle identical to the 256²
// kernel. Epilogue: R7 ni-inner bf16 stores.
// ============================================================================
__global__ __launch_bounds__(256, 2)
void gemm_mlp1(const unsigned short* __restrict__ A,     // xb  [16384][1024]
               const unsigned short* __restrict__ Bt,    // w1t [E][4096][1024]
               const float* __restrict__ bias,           // b1  [E][4096]
               unsigned short* __restrict__ Out) {       // hb  [16384][4096]
  constexpr int K = D_;        // 1024
  constexpr int NCOLS = H_;    // 4096
  constexpr int NT = K / 64;   // 16 (even)
  constexpr int MT = 16;       // 2048/128 m-tiles per expert
  constexpr int NTL = 32;      // 4096/128 n-tiles per expert

  __shared__ __align__(16) unsigned short A0k0[4096], A0k1[4096], B0k0[4096], B0k1[4096];
  __shared__ __align__(16) unsigned short A1k0[4096], A1k1[4096], B1k0[4096], B1k1[4096];

  const int nwg = gridDim.x;               // 4096, %8==0
  const int flat = blockIdx.x;
  const int swz = (flat & 7) * (nwg >> 3) + (flat >> 3);
  const int e = swz / (MT * NTL);
  const int rem = swz - e * (MT * NTL);
  const int nt = rem >> 4;                 // /MT
  const int mt = rem & 15;

  const int m0 = mt * 128;
  const int b = m0 >> 10;
  const int nl = m0 & 1023;
  const size_t arow0 = (size_t)((b * E_ + e) * N_ + nl);
  const int n0 = nt * 128;

  const int tid = threadIdx.x;
  const int w = tid >> 6;                  // 0..3
  const int lane = tid & 63;
  const int wr = w >> 1;                   // M half (64 rows)
  const int wc = w & 1;                    // N half (64 cols)
  const int fr = lane & 15;
  const int kg = lane >> 4;
  const int sxor = kg ^ ((lane >> 1) & 3);

  const int scol = (((lane & 3) ^ ((lane >> 3) & 3)) << 3);
  const int srow0 = w * 32 + (lane >> 2);  // 0..127
  const int srow1 = srow0 + 16;
  const unsigned short* aS0 = A + (arow0 + srow0) * K + scol;
  const unsigned short* aS1 = A + (arow0 + srow1) * K + scol;
  const unsigned short* bS0 = Bt + ((size_t)e * NCOLS + n0 + srow0) * K + scol;
  const unsigned short* bS1 = Bt + ((size_t)e * NCOLS + n0 + srow1) * K + scol;

  const int aBase = (wr * 64 + fr) * 32 + sxor * 8;
  const int bBase = (wc * 64 + fr) * 32 + sxor * 8;
  const int rb = kg * 4;

#define STAGE(ARR, S0_, S1_, t, kh) do {                           \
    const size_t ko_ = (size_t)(t) * 64 + (kh) * 32;               \
    gload_lds16(S0_ + ko_, &ARR[w * 1024]);                        \
    gload_lds16(S1_ + ko_, &ARR[w * 1024 + 512]);                  \
  } while (0)

  f32x4 acc[4][4];
#pragma unroll
  for (int i = 0; i < 4; ++i)
#pragma unroll
    for (int j = 0; j < 4; ++j)
      acc[i][j] = (f32x4){0.f, 0.f, 0.f, 0.f};

  // prologue: tile0 into buf0 (k0 first, then k1); k0 visible, k1 in flight
  STAGE(A0k0, aS0, aS1, 0, 0); STAGE(B0k0, bS0, bS1, 0, 0);
  STAGE(A0k1, aS0, aS1, 0, 1); STAGE(B0k1, bS0, bS1, 0, 1);
  asm volatile("s_waitcnt vmcnt(4)" ::: "memory");
  __builtin_amdgcn_s_barrier();

#define MFMA16()                                                              \
    __builtin_amdgcn_s_setprio(1);                                            \
    _Pragma("unroll")                                                         \
    for (int mi = 0; mi < 4; ++mi)                                            \
      _Pragma("unroll")                                                       \
      for (int ni = 0; ni < 4; ++ni)                                          \
        acc[mi][ni] =                                                         \
            __builtin_amdgcn_mfma_f32_16x16x32_bf16(av[mi], bv[ni],           \
                                                    acc[mi][ni], 0, 0, 0);    \
    __builtin_amdgcn_s_setprio(0);

#define KTILE(t, CAk0, CAk1, CBk0, CBk1, NAk0, NAk1, NBk0, NBk1) do {         \
    bf16x8 av[4], bv[4];                                                      \
    /* P1: kh=0. In flight entering: 4 (c.k1 of tile t). */                   \
    _Pragma("unroll")                                                         \
    for (int i = 0; i < 4; ++i) {                                             \
      av[i] = lds_read_b128((lds_cus*)&CAk0[aBase + i * 512]);                \
      bv[i] = lds_read_b128((lds_cus*)&CBk0[bBase + i * 512]);                \
    }                                                                         \
    if ((t) + 1 < NT) { STAGE(NAk0, aS0, aS1, (t) + 1, 0);                    \
                        STAGE(NBk0, bS0, bS1, (t) + 1, 0); }                  \
    asm volatile("s_waitcnt lgkmcnt(0)");                                     \
    __builtin_amdgcn_sched_barrier(0);                                        \
    MFMA16()                                                                  \
    /* retire k1(t) (oldest 4); k0(t+1) may stay in flight */                 \
    if ((t) + 1 < NT) { asm volatile("s_waitcnt vmcnt(4)" ::: "memory"); }    \
    else              { asm volatile("s_waitcnt vmcnt(0)" ::: "memory"); }    \
    __builtin_amdgcn_s_barrier();                                             \
    /* P2: kh=1. */                                                           \
    _Pragma("unroll")                                                         \
    for (int i = 0; i < 4; ++i) {                                             \
      av[i] = lds_read_b128((lds_cus*)&CAk1[aBase + i * 512]);                \
      bv[i] = lds_read_b128((lds_cus*)&CBk1[bBase + i * 512]);                \
    }                                                                         \
    if ((t) + 1 < NT) { STAGE(NAk1, aS0, aS1, (t) + 1, 1);                    \
                        STAGE(NBk1, bS0, bS1, (t) + 1, 1); }                  \
    asm volatile("s_waitcnt lgkmcnt(0)");                                     \
    __builtin_amdgcn_sched_barrier(0);                                        \
    MFMA16()                                                                  \
    /* retire k0(t+1) (oldest 4); k1(t+1) may stay in flight */               \
    if ((t) + 1 < NT) { asm volatile("s_waitcnt vmcnt(4)" ::: "memory"); }    \
    else              { asm volatile("s_waitcnt vmcnt(0)" ::: "memory"); }    \
    __builtin_amdgcn_s_barrier();                                             \
  } while (0)

#pragma unroll 1
  for (int tt = 0; tt < NT; tt += 2) {
    KTILE(tt,     A0k0, A0k1, B0k0, B0k1, A1k0, A1k1, B1k0, B1k1);
    KTILE(tt + 1, A1k0, A1k1, B1k0, B1k1, A0k0, A0k1, B0k0, B0k1);
  }

#undef KTILE
#undef MFMA16
#undef STAGE

  // epilogue: C/D layout col=lane&15, row=(lane>>4)*4+j; ni-inner (R7)
  float bval[4];
#pragma unroll
  for (int ni = 0; ni < 4; ++ni)
    bval[ni] = bias[(size_t)e * NCOLS + n0 + wc * 64 + ni * 16 + fr];
  const size_t gcb = (size_t)n0 + wc * 64 + fr;
#pragma unroll
  for (int mi = 0; mi < 4; ++mi) {
#pragma unroll
    for (int j = 0; j < 4; ++j) {
      const size_t orow = arow0 + (size_t)(wr * 64 + mi * 16 + rb + j);
      unsigned short* rp = Out + orow * NCOLS + gcb;
#pragma unroll
      for (int ni = 0; ni < 4; ++ni)
        rp[ni * 16] = f2bf(gelu_fast(acc[mi][ni][j] + bval[ni]));
    }
  }
}

// ============================================================================
// GEMM2 (unchanged R4 structure): 256x256, BK=64, 8 waves, 4-phase/K-tile,
// named LDS arrays (128KB), fp32 direct stores.
// ============================================================================
__global__ __launch_bounds__(512, 2)
void gemm_mlp2(const unsigned short* __restrict__ A,     // hb  [16384][4096]
               const unsigned short* __restrict__ Bt,    // w2t [E][1024][4096]
               const float* __restrict__ bias,           // b2  [E][1024]
               float* __restrict__ OutF) {               // out [16384][1024]
  constexpr int K = H_;        // 4096
  constexpr int NCOLS = D_;    // 1024
  constexpr int NT = K / 64;   // 64
  constexpr int MT = 8;
  constexpr int NTL = 4;

  __shared__ __align__(16) unsigned short A0k0[8192], A0k1[8192], B0k0[8192], B0k1[8192];
  __shared__ __align__(16) unsigned short A1k0[8192], A1k1[8192], B1k0[8192], B1k1[8192];

  const int nwg = gridDim.x;
  const int flat = blockIdx.x;
  const int swz = (flat & 7) * (nwg >> 3) + (flat >> 3);
  const int e = swz / (MT * NTL);
  const int rem = swz - e * (MT * NTL);
  const int nt = rem / MT;
  const int mt = rem - nt * MT;

  const int m0 = mt * 256;
  const int b = m0 >> 10;
  const int nl = m0 & 1023;
  const size_t arow0 = (size_t)((b * E_ + e) * N_ + nl);
  const int n0 = nt * 256;

  const unsigned short* Ab = A + arow0 * K;
  const unsigned short* Bb = Bt + ((size_t)e * NCOLS + n0) * K;

  const int tid = threadIdx.x;
  const int w = tid >> 6;
  const int lane = tid & 63;
  const int wr = w >> 2;
  const int wc = w & 3;
  const int fr = lane & 15;
  const int kg = lane >> 4;
  const int sxor = kg ^ ((lane >> 1) & 3);

  const int scol = (((lane & 3) ^ ((lane >> 3) & 3)) << 3);
  const int srow0 = w * 32 + (lane >> 2);
  const int srow1 = srow0 + 16;
  const unsigned short* aS0 = Ab + (size_t)srow0 * K + scol;
  const unsigned short* aS1 = Ab + (size_t)srow1 * K + scol;
  const unsigned short* bS0 = Bb + (size_t)srow0 * K + scol;
  const unsigned short* bS1 = Bb + (size_t)srow1 * K + scol;

  const int aBase = (wr * 128 + fr) * 32 + sxor * 8;
  const int bBase = (wc * 64 + fr) * 32 + sxor * 8;
  const int rb = kg * 4;

#define STAGE(ARR, S0_, S1_, t, kh) do {                           \
    const size_t ko_ = (size_t)(t) * 64 + (kh) * 32;               \
    gload_lds16(S0_ + ko_, &ARR[w * 1024]);                        \
    gload_lds16(S1_ + ko_, &ARR[w * 1024 + 512]);                  \
  } while (0)

#define WAIT_LGKM() do {                                                      \
    asm volatile("s_waitcnt lgkmcnt(0)");                                     \
    __builtin_amdgcn_sched_barrier(0);                                        \
  } while (0)

#define MFMA_CLUSTER(ROFF)                                                    \
    __builtin_amdgcn_s_setprio(1);                                            \
    _Pragma("unroll")                                                         \
    for (int mi = 0; mi < 4; ++mi)                                            \
      _Pragma("unroll")                                                       \
      for (int ni = 0; ni < 4; ++ni)                                          \
        acc[(ROFF) + mi][ni] =                                                \
            __builtin_amdgcn_mfma_f32_16x16x32_bf16(av[mi], bv[ni],           \
                                                    acc[(ROFF) + mi][ni], 0, 0, 0); \
    __builtin_amdgcn_s_setprio(0);

#define ITER(t, CA0, CA1, CB0, CB1, NA1, NB1) do {                            \
    bf16x8 av[4], bv[4];                                                      \
    _Pragma("unroll")                                                         \
    for (int i = 0; i < 4; ++i) {                                             \
      av[i] = lds_read_b128((lds_cus*)&CA0[aBase + i * 512]);                 \
      bv[i] = lds_read_b128((lds_cus*)&CB0[bBase + i * 512]);                 \
    }                                                                         \
    if ((t) + 1 < NT) STAGE(NA1, aS0, aS1, (t) + 1, 1);                       \
    __builtin_amdgcn_s_barrier();                                             \
    WAIT_LGKM();                                                              \
    MFMA_CLUSTER(0)                                                           \
    __builtin_amdgcn_s_barrier();                                             \
    _Pragma("unroll")                                                         \
    for (int i = 0; i < 4; ++i)                                               \
      av[i] = lds_read_b128((lds_cus*)&CA0[aBase + 2048 + i * 512]);          \
    if ((t) + 1 < NT) STAGE(NB1, bS0, bS1, (t) + 1, 1);                       \
    __builtin_amdgcn_s_barrier();                                             \
    WAIT_LGKM();                                                              \
    MFMA_CLUSTER(4)                                                           \
    __builtin_amdgcn_s_barrier();                                             \
    _Pragma("unroll")                                                         \
    for (int i = 0; i < 4; ++i) {                                             \
      av[i] = lds_read_b128((lds_cus*)&CA1[aBase + i * 512]);                 \
      bv[i] = lds_read_b128((lds_cus*)&CB1[bBase + i * 512]);                 \
    }                                                                         \
    if ((t) + 2 < NT) STAGE(CA0, aS0, aS1, (t) + 2, 0);                       \
    __builtin_amdgcn_s_barrier();                                             \
    WAIT_LGKM();                                                              \
    MFMA_CLUSTER(0)                                                           \
    __builtin_amdgcn_s_barrier();                                             \
    _Pragma("unroll")                                                         \
    for (int i = 0; i < 4; ++i)                                               \
      av[i] = lds_read_b128((lds_cus*)&CA1[aBase + 2048 + i * 512]);          \
    if ((t) + 2 < NT) STAGE(CB0, bS0, bS1, (t) + 2, 0);                       \
    __builtin_amdgcn_s_barrier();                                             \
    WAIT_LGKM();                                                              \
    MFMA_CLUSTER(4)                                                           \
    if ((t) + 2 < NT) { asm volatile("s_waitcnt vmcnt(4)" ::: "memory"); }    \
    else              { asm volatile("s_waitcnt vmcnt(0)" ::: "memory"); }    \
    __builtin_amdgcn_s_barrier();                                             \
  } while (0)

  f32x4 acc[8][4];
#pragma unroll
  for (int i = 0; i < 8; ++i)
#pragma unroll
    for (int j = 0; j < 4; ++j)
      acc[i][j] = (f32x4){0.f, 0.f, 0.f, 0.f};

  STAGE(A0k0, aS0, aS1, 0, 0); STAGE(B0k0, bS0, bS1, 0, 0);
  STAGE(A0k1, aS0, aS1, 0, 1); STAGE(B0k1, bS0, bS1, 0, 1);
  STAGE(A1k0, aS0, aS1, 1, 0); STAGE(B1k0, bS0, bS1, 1, 0);
  asm volatile("s_waitcnt vmcnt(4)" ::: "memory");
  __builtin_amdgcn_s_barrier();

#pragma unroll 1
  for (int tt = 0; tt < NT; tt += 2) {
    ITER(tt,     A0k0, A0k1, B0k0, B0k1, A1k1, B1k1);
    ITER(tt + 1, A1k0, A1k1, B1k0, B1k1, A0k1, B0k1);
  }

#undef ITER
#undef MFMA_CLUSTER
#undef WAIT_LGKM
#undef STAGE

#pragma unroll
  for (int ni = 0; ni < 4; ++ni) {
    const int gc = n0 + wc * 64 + ni * 16 + fr;
    const float bval = bias[(size_t)e * NCOLS + gc];
#pragma unroll
    for (int MI = 0; MI < 8; ++MI) {
      const size_t orow = arow0 + (size_t)(wr * 128 + MI * 16 + rb);
#pragma unroll
      for (int j = 0; j < 4; ++j)
        OutF[(orow + j) * NCOLS + gc] = acc[MI][ni][j] + bval;
    }
  }
}

extern "C" void kernel_launch(void* const* d_in, const int* in_sizes, int n_in,
                              void* d_out, int out_size, void* d_ws, size_t ws_size,
                              hipStream_t stream) {
  const float* x  = (const float*)d_in[0];
  const float* w1 = (const float*)d_in[1];
  const float* b1 = (const float*)d_in[2];
  const float* w2 = (const float*)d_in[3];
  const float* b2 = (const float*)d_in[4];
  float* out = (float*)d_out;

  const size_t xN  = (size_t)B_ * E_ * N_ * D_;
  const size_t w1N = (size_t)E_ * D_ * H_;
  const size_t w2N = (size_t)E_ * H_ * D_;
  const size_t hN  = (size_t)B_ * E_ * N_ * H_;
  const size_t needed = (xN + w1N + w2N + hN) * 2;
  if (ws_size < needed) return;

  unsigned short* xb  = (unsigned short*)d_ws;
  unsigned short* w1t = xb + xN;   // [E][H][D] bf16
  unsigned short* w2t = w1t + w1N; // [E][D][H] bf16
  unsigned short* hb  = w2t + w2N; // [B][E][N][H] bf16

  dim3 tb(32, 8);
  transpose_cvt_kernel<<<dim3(D_ / 32, H_ / 32, E_), tb, 0, stream>>>(w2, w2t, H_, D_);
  transpose_cvt_kernel<<<dim3(H_ / 32, D_ / 32, E_), tb, 0, stream>>>(w1, w1t, D_, H_);
  cvt_x_kernel<<<2048, 256, 0, stream>>>(x, xb, (int)(xN / 4));

  // GEMM1: 128² tiles -> 8e x 16mt x 32nt = 4096 blocks, 2 blocks/CU
  gemm_mlp1<<<E_ * 16 * 32, 256, 0, stream>>>(xb, w1t, b1, hb);
  // GEMM2: 256² tiles -> 256 blocks
  gemm_mlp2<<<E_ * 8 * (D_ / 256), 512, 0, stream>>>(hb, w2t, b2, out);
}

// Round 11
// 462.698 us; speedup vs baseline: 1.0001x; 1.0001x over previous
//
#include <hip/hip_runtime.h>
#include <stdint.h>

#define B_ 2
#define E_ 8
#define N_ 1024
#define D_ 1024
#define H_ 4096

typedef float f32x4 __attribute__((ext_vector_type(4)));
typedef __bf16 bf16x8 __attribute__((ext_vector_type(8)));
typedef unsigned int u32x4 __attribute__((ext_vector_type(4)));
typedef __attribute__((address_space(3))) const unsigned short lds_cus;

__device__ __forceinline__ unsigned short f2bf(float f) {
  union { float f; uint32_t u; } v; v.f = f;
  uint32_t u = v.u;
  return (unsigned short)((u + 0x7FFFu + ((u >> 16) & 1u)) >> 16);  // RNE
}

// tanh-form GELU (max |delta| vs exact erf-GELU ~1e-3, inside threshold headroom)
__device__ __forceinline__ float gelu_fast(float x) {
  float x3 = x * x * x;
  float y = 0.79788456080286536f * (x + 0.044715f * x3);
  float e = __expf(2.0f * y);
  float t = 1.0f - 2.0f / (e + 1.0f);   // tanh(y)
  return 0.5f * x * (1.0f + t);
}

__device__ __forceinline__ void gload_lds16(const unsigned short* g, unsigned short* l) {
  __builtin_amdgcn_global_load_lds(
      (__attribute__((address_space(1))) void*)g,
      (__attribute__((address_space(3))) void*)l,
      16, 0, 0);
}

__device__ __forceinline__ bf16x8 lds_read_b128(lds_cus* p) {
  bf16x8 r;
  asm volatile("ds_read_b128 %0, %1" : "=v"(r) : "v"(p));
  return r;
}

// ---- elementwise fp32 -> bf16 convert (x) ----
__global__ void cvt_x_kernel(const float* __restrict__ in, unsigned short* __restrict__ out, int n4) {
  int idx = blockIdx.x * blockDim.x + threadIdx.x;
  int stride = gridDim.x * blockDim.x;
  const float4* in4 = (const float4*)in;
  ushort4* out4 = (ushort4*)out;
  for (int i = idx; i < n4; i += stride) {
    float4 f = in4[i];
    ushort4 o;
    o.x = f2bf(f.x); o.y = f2bf(f.y); o.z = f2bf(f.z); o.w = f2bf(f.w);
    out4[i] = o;
  }
}

// ---- tiled transpose + convert: in fp32 [R][C] per expert -> out bf16 [C][R] ----
__global__ void transpose_cvt_kernel(const float* __restrict__ in, unsigned short* __restrict__ out,
                                     int R, int C) {
  __shared__ float tile[32][33];
  const size_t eoff = (size_t)blockIdx.z * R * C;
  const float* src = in + eoff;
  unsigned short* dst = out + eoff;
  const int c0 = blockIdx.x * 32, r0 = blockIdx.y * 32;
  const int tx = threadIdx.x, ty = threadIdx.y;
#pragma unroll
  for (int i = 0; i < 4; ++i)
    tile[ty + 8 * i][tx] = src[(size_t)(r0 + ty + 8 * i) * C + c0 + tx];
  __syncthreads();
#pragma unroll
  for (int i = 0; i < 4; ++i)
    dst[(size_t)(c0 + ty + 8 * i) * R + r0 + tx] = f2bf(tile[tx][ty + 8 * i]);
}

// ============================================================================
// GEMM1 (R11): 128x128 tile, BK=64, 4 waves, dbuf, 64KB LDS, 2 blocks/CU
// (R10 K-loop unchanged). NEW: epilogue repacks the output tile through the
// idle staging LDS (single 64KB array; repack view [128][136] = 34.8KB) and
// stores via 16B/lane NONTEMPORAL dwordx4 -- full 128B lines, no
// write-allocate line fills (R10 FETCH showed +134MB = hb-sized RFO reads).
// ============================================================================
__global__ __launch_bounds__(256, 2)
void gemm_mlp1(const unsigned short* __restrict__ A,     // xb  [16384][1024]
               const unsigned short* __restrict__ Bt,    // w1t [E][4096][1024]
               const float* __restrict__ bias,           // b1  [E][4096]
               unsigned short* __restrict__ Out) {       // hb  [16384][4096]
  constexpr int K = D_;        // 1024
  constexpr int NCOLS = H_;    // 4096
  constexpr int NT = K / 64;   // 16 (even)
  constexpr int MT = 16;
  constexpr int NTL = 32;
  constexpr int EPI_LD = 136;  // 128 + 8 pad

  __shared__ __align__(16) unsigned short LDSU[32768];   // 64 KiB
  unsigned short* const A0k0 = LDSU;
  unsigned short* const A0k1 = LDSU + 4096;
  unsigned short* const B0k0 = LDSU + 8192;
  unsigned short* const B0k1 = LDSU + 12288;
  unsigned short* const A1k0 = LDSU + 16384;
  unsigned short* const A1k1 = LDSU + 20480;
  unsigned short* const B1k0 = LDSU + 24576;
  unsigned short* const B1k1 = LDSU + 28672;

  const int nwg = gridDim.x;               // 4096, %8==0
  const int flat = blockIdx.x;
  const int swz = (flat & 7) * (nwg >> 3) + (flat >> 3);
  const int e = swz / (MT * NTL);
  const int rem = swz - e * (MT * NTL);
  const int nt = rem >> 4;
  const int mt = rem & 15;

  const int m0 = mt * 128;
  const int b = m0 >> 10;
  const int nl = m0 & 1023;
  const size_t arow0 = (size_t)((b * E_ + e) * N_ + nl);
  const int n0 = nt * 128;

  const int tid = threadIdx.x;
  const int w = tid >> 6;                  // 0..3
  const int lane = tid & 63;
  const int wr = w >> 1;
  const int wc = w & 1;
  const int fr = lane & 15;
  const int kg = lane >> 4;
  const int sxor = kg ^ ((lane >> 1) & 3);

  const int scol = (((lane & 3) ^ ((lane >> 3) & 3)) << 3);
  const int srow0 = w * 32 + (lane >> 2);
  const int srow1 = srow0 + 16;
  const unsigned short* aS0 = A + (arow0 + srow0) * K + scol;
  const unsigned short* aS1 = A + (arow0 + srow1) * K + scol;
  const unsigned short* bS0 = Bt + ((size_t)e * NCOLS + n0 + srow0) * K + scol;
  const unsigned short* bS1 = Bt + ((size_t)e * NCOLS + n0 + srow1) * K + scol;

  const int aBase = (wr * 64 + fr) * 32 + sxor * 8;
  const int bBase = (wc * 64 + fr) * 32 + sxor * 8;
  const int rb = kg * 4;

#define STAGE(ARR, S0_, S1_, t, kh) do {                           \
    const size_t ko_ = (size_t)(t) * 64 + (kh) * 32;               \
    gload_lds16(S0_ + ko_, &ARR[w * 1024]);                        \
    gload_lds16(S1_ + ko_, &ARR[w * 1024 + 512]);                  \
  } while (0)

  f32x4 acc[4][4];
#pragma unroll
  for (int i = 0; i < 4; ++i)
#pragma unroll
    for (int j = 0; j < 4; ++j)
      acc[i][j] = (f32x4){0.f, 0.f, 0.f, 0.f};

  STAGE(A0k0, aS0, aS1, 0, 0); STAGE(B0k0, bS0, bS1, 0, 0);
  STAGE(A0k1, aS0, aS1, 0, 1); STAGE(B0k1, bS0, bS1, 0, 1);
  asm volatile("s_waitcnt vmcnt(4)" ::: "memory");
  __builtin_amdgcn_s_barrier();

#define MFMA16()                                                              \
    __builtin_amdgcn_s_setprio(1);                                            \
    _Pragma("unroll")                                                         \
    for (int mi = 0; mi < 4; ++mi)                                            \
      _Pragma("unroll")                                                       \
      for (int ni = 0; ni < 4; ++ni)                                          \
        acc[mi][ni] =                                                         \
            __builtin_amdgcn_mfma_f32_16x16x32_bf16(av[mi], bv[ni],           \
                                                    acc[mi][ni], 0, 0, 0);    \
    __builtin_amdgcn_s_setprio(0);

#define KTILE(t, CAk0, CAk1, CBk0, CBk1, NAk0, NAk1, NBk0, NBk1) do {         \
    bf16x8 av[4], bv[4];                                                      \
    _Pragma("unroll")                                                         \
    for (int i = 0; i < 4; ++i) {                                             \
      av[i] = lds_read_b128((lds_cus*)&CAk0[aBase + i * 512]);                \
      bv[i] = lds_read_b128((lds_cus*)&CBk0[bBase + i * 512]);                \
    }                                                                         \
    if ((t) + 1 < NT) { STAGE(NAk0, aS0, aS1, (t) + 1, 0);                    \
                        STAGE(NBk0, bS0, bS1, (t) + 1, 0); }                  \
    asm volatile("s_waitcnt lgkmcnt(0)");                                     \
    __builtin_amdgcn_sched_barrier(0);                                        \
    MFMA16()                                                                  \
    if ((t) + 1 < NT) { asm volatile("s_waitcnt vmcnt(4)" ::: "memory"); }    \
    else              { asm volatile("s_waitcnt vmcnt(0)" ::: "memory"); }    \
    __builtin_amdgcn_s_barrier();                                             \
    _Pragma("unroll")                                                         \
    for (int i = 0; i < 4; ++i) {                                             \
      av[i] = lds_read_b128((lds_cus*)&CAk1[aBase + i * 512]);                \
      bv[i] = lds_read_b128((lds_cus*)&CBk1[bBase + i * 512]);                \
    }                                                                         \
    if ((t) + 1 < NT) { STAGE(NAk1, aS0, aS1, (t) + 1, 1);                    \
                        STAGE(NBk1, bS0, bS1, (t) + 1, 1); }                  \
    asm volatile("s_waitcnt lgkmcnt(0)");                                     \
    __builtin_amdgcn_sched_barrier(0);                                        \
    MFMA16()                                                                  \
    if ((t) + 1 < NT) { asm volatile("s_waitcnt vmcnt(4)" ::: "memory"); }    \
    else              { asm volatile("s_waitcnt vmcnt(0)" ::: "memory"); }    \
    __builtin_amdgcn_s_barrier();                                             \
  } while (0)

#pragma unroll 1
  for (int tt = 0; tt < NT; tt += 2) {
    KTILE(tt,     A0k0, A0k1, B0k0, B0k1, A1k0, A1k1, B1k0, B1k1);
    KTILE(tt + 1, A1k0, A1k1, B1k0, B1k1, A0k0, A0k1, B0k0, B0k1);
  }

#undef KTILE
#undef MFMA16
#undef STAGE

  // ---- R11 epilogue: gelu -> LDS repack -> nontemporal full-line stores ----
  // K-loop's final vmcnt(0)+barrier guarantees all staging reads are done.
  float bval[4];
#pragma unroll
  for (int ni = 0; ni < 4; ++ni)
    bval[ni] = bias[(size_t)e * NCOLS + n0 + wc * 64 + ni * 16 + fr];
#pragma unroll
  for (int mi = 0; mi < 4; ++mi) {
#pragma unroll
    for (int j = 0; j < 4; ++j) {
      const int row = wr * 64 + mi * 16 + rb + j;
#pragma unroll
      for (int ni = 0; ni < 4; ++ni) {
        const int col = wc * 64 + ni * 16 + fr;
        LDSU[row * EPI_LD + col] = f2bf(gelu_fast(acc[mi][ni][j] + bval[ni]));
      }
    }
  }
  __syncthreads();
  // Wave w streams rows [w*32, w*32+32): 4 rows/instr (lane>>4), 16 lanes x
  // 16B = 256B contiguous per row, nontemporal (no write-allocate).
  const int l4 = lane >> 4, l15 = lane & 15;
#pragma unroll
  for (int it = 0; it < 8; ++it) {
    const int row = w * 32 + it * 4 + l4;
    u32x4 vv = *(const u32x4*)&LDSU[row * EPI_LD + l15 * 8];
    __builtin_nontemporal_store(vv,
        (u32x4*)&Out[(arow0 + row) * NCOLS + n0 + l15 * 8]);
  }
}

// ============================================================================
// GEMM2 (R4 structure unchanged; stores now nontemporal): 256x256, BK=64,
// 8 waves, 4-phase/K-tile, named LDS arrays (128KB).
// ============================================================================
__global__ __launch_bounds__(512, 2)
void gemm_mlp2(const unsigned short* __restrict__ A,     // hb  [16384][4096]
               const unsigned short* __restrict__ Bt,    // w2t [E][1024][4096]
               const float* __restrict__ bias,           // b2  [E][1024]
               float* __restrict__ OutF) {               // out [16384][1024]
  constexpr int K = H_;
  constexpr int NCOLS = D_;
  constexpr int NT = K / 64;
  constexpr int MT = 8;
  constexpr int NTL = 4;

  __shared__ __align__(16) unsigned short A0k0[8192], A0k1[8192], B0k0[8192], B0k1[8192];
  __shared__ __align__(16) unsigned short A1k0[8192], A1k1[8192], B1k0[8192], B1k1[8192];

  const int nwg = gridDim.x;
  const int flat = blockIdx.x;
  const int swz = (flat & 7) * (nwg >> 3) + (flat >> 3);
  const int e = swz / (MT * NTL);
  const int rem = swz - e * (MT * NTL);
  const int nt = rem / MT;
  const int mt = rem - nt * MT;

  const int m0 = mt * 256;
  const int b = m0 >> 10;
  const int nl = m0 & 1023;
  const size_t arow0 = (size_t)((b * E_ + e) * N_ + nl);
  const int n0 = nt * 256;

  const unsigned short* Ab = A + arow0 * K;
  const unsigned short* Bb = Bt + ((size_t)e * NCOLS + n0) * K;

  const int tid = threadIdx.x;
  const int w = tid >> 6;
  const int lane = tid & 63;
  const int wr = w >> 2;
  const int wc = w & 3;
  const int fr = lane & 15;
  const int kg = lane >> 4;
  const int sxor = kg ^ ((lane >> 1) & 3);

  const int scol = (((lane & 3) ^ ((lane >> 3) & 3)) << 3);
  const int srow0 = w * 32 + (lane >> 2);
  const int srow1 = srow0 + 16;
  const unsigned short* aS0 = Ab + (size_t)srow0 * K + scol;
  const unsigned short* aS1 = Ab + (size_t)srow1 * K + scol;
  const unsigned short* bS0 = Bb + (size_t)srow0 * K + scol;
  const unsigned short* bS1 = Bb + (size_t)srow1 * K + scol;

  const int aBase = (wr * 128 + fr) * 32 + sxor * 8;
  const int bBase = (wc * 64 + fr) * 32 + sxor * 8;
  const int rb = kg * 4;

#define STAGE(ARR, S0_, S1_, t, kh) do {                           \
    const size_t ko_ = (size_t)(t) * 64 + (kh) * 32;               \
    gload_lds16(S0_ + ko_, &ARR[w * 1024]);                        \
    gload_lds16(S1_ + ko_, &ARR[w * 1024 + 512]);                  \
  } while (0)

#define WAIT_LGKM() do {                                                      \
    asm volatile("s_waitcnt lgkmcnt(0)");                                     \
    __builtin_amdgcn_sched_barrier(0);                                        \
  } while (0)

#define MFMA_CLUSTER(ROFF)                                                    \
    __builtin_amdgcn_s_setprio(1);                                            \
    _Pragma("unroll")                                                         \
    for (int mi = 0; mi < 4; ++mi)                                            \
      _Pragma("unroll")                                                       \
      for (int ni = 0; ni < 4; ++ni)                                          \
        acc[(ROFF) + mi][ni] =                                                \
            __builtin_amdgcn_mfma_f32_16x16x32_bf16(av[mi], bv[ni],           \
                                                    acc[(ROFF) + mi][ni], 0, 0, 0); \
    __builtin_amdgcn_s_setprio(0);

#define ITER(t, CA0, CA1, CB0, CB1, NA1, NB1) do {                            \
    bf16x8 av[4], bv[4];                                                      \
    _Pragma("unroll")                                                         \
    for (int i = 0; i < 4; ++i) {                                             \
      av[i] = lds_read_b128((lds_cus*)&CA0[aBase + i * 512]);                 \
      bv[i] = lds_read_b128((lds_cus*)&CB0[bBase + i * 512]);                 \
    }                                                                         \
    if ((t) + 1 < NT) STAGE(NA1, aS0, aS1, (t) + 1, 1);                       \
    __builtin_amdgcn_s_barrier();                                             \
    WAIT_LGKM();                                                              \
    MFMA_CLUSTER(0)                                                           \
    __builtin_amdgcn_s_barrier();                                             \
    _Pragma("unroll")                                                         \
    for (int i = 0; i < 4; ++i)                                               \
      av[i] = lds_read_b128((lds_cus*)&CA0[aBase + 2048 + i * 512]);          \
    if ((t) + 1 < NT) STAGE(NB1, bS0, bS1, (t) + 1, 1);                       \
    __builtin_amdgcn_s_barrier();                                             \
    WAIT_LGKM();                                                              \
    MFMA_CLUSTER(4)                                                           \
    __builtin_amdgcn_s_barrier();                                             \
    _Pragma("unroll")                                                         \
    for (int i = 0; i < 4; ++i) {                                             \
      av[i] = lds_read_b128((lds_cus*)&CA1[aBase + i * 512]);                 \
      bv[i] = lds_read_b128((lds_cus*)&CB1[bBase + i * 512]);                 \
    }                                                                         \
    if ((t) + 2 < NT) STAGE(CA0, aS0, aS1, (t) + 2, 0);                       \
    __builtin_amdgcn_s_barrier();                                             \
    WAIT_LGKM();                                                              \
    MFMA_CLUSTER(0)                                                           \
    __builtin_amdgcn_s_barrier();                                             \
    _Pragma("unroll")                                                         \
    for (int i = 0; i < 4; ++i)                                               \
      av[i] = lds_read_b128((lds_cus*)&CA1[aBase + 2048 + i * 512]);          \
    if ((t) + 2 < NT) STAGE(CB0, bS0, bS1, (t) + 2, 0);                       \
    __builtin_amdgcn_s_barrier();                                             \
    WAIT_LGKM();                                                              \
    MFMA_CLUSTER(4)                                                           \
    if ((t) + 2 < NT) { asm volatile("s_waitcnt vmcnt(4)" ::: "memory"); }    \
    else              { asm volatile("s_waitcnt vmcnt(0)" ::: "memory"); }    \
    __builtin_amdgcn_s_barrier();                                             \
  } while (0)

  f32x4 acc[8][4];
#pragma unroll
  for (int i = 0; i < 8; ++i)
#pragma unroll
    for (int j = 0; j < 4; ++j)
      acc[i][j] = (f32x4){0.f, 0.f, 0.f, 0.f};

  STAGE(A0k0, aS0, aS1, 0, 0); STAGE(B0k0, bS0, bS1, 0, 0);
  STAGE(A0k1, aS0, aS1, 0, 1); STAGE(B0k1, bS0, bS1, 0, 1);
  STAGE(A1k0, aS0, aS1, 1, 0); STAGE(B1k0, bS0, bS1, 1, 0);
  asm volatile("s_waitcnt vmcnt(4)" ::: "memory");
  __builtin_amdgcn_s_barrier();

#pragma unroll 1
  for (int tt = 0; tt < NT; tt += 2) {
    ITER(tt,     A0k0, A0k1, B0k0, B0k1, A1k1, B1k1);
    ITER(tt + 1, A1k0, A1k1, B1k0, B1k1, A0k1, B0k1);
  }

#undef ITER
#undef MFMA_CLUSTER
#undef WAIT_LGKM
#undef STAGE

#pragma unroll
  for (int ni = 0; ni < 4; ++ni) {
    const int gc = n0 + wc * 64 + ni * 16 + fr;
    const float bval = bias[(size_t)e * NCOLS + gc];
#pragma unroll
    for (int MI = 0; MI < 8; ++MI) {
      const size_t orow = arow0 + (size_t)(wr * 128 + MI * 16 + rb);
#pragma unroll
      for (int j = 0; j < 4; ++j)
        __builtin_nontemporal_store(acc[MI][ni][j] + bval,
                                    &OutF[(orow + j) * NCOLS + gc]);
    }
  }
}

extern "C" void kernel_launch(void* const* d_in, const int* in_sizes, int n_in,
                              void* d_out, int out_size, void* d_ws, size_t ws_size,
                              hipStream_t stream) {
  const float* x  = (const float*)d_in[0];
  const float* w1 = (const float*)d_in[1];
  const float* b1 = (const float*)d_in[2];
  const float* w2 = (const float*)d_in[3];
  const float* b2 = (const float*)d_in[4];
  float* out = (float*)d_out;

  const size_t xN  = (size_t)B_ * E_ * N_ * D_;
  const size_t w1N = (size_t)E_ * D_ * H_;
  const size_t w2N = (size_t)E_ * H_ * D_;
  const size_t hN  = (size_t)B_ * E_ * N_ * H_;
  const size_t needed = (xN + w1N + w2N + hN) * 2;
  if (ws_size < needed) return;

  unsigned short* xb  = (unsigned short*)d_ws;
  unsigned short* w1t = xb + xN;   // [E][H][D] bf16
  unsigned short* w2t = w1t + w1N; // [E][D][H] bf16
  unsigned short* hb  = w2t + w2N; // [B][E][N][H] bf16

  dim3 tb(32, 8);
  transpose_cvt_kernel<<<dim3(D_ / 32, H_ / 32, E_), tb, 0, stream>>>(w2, w2t, H_, D_);
  transpose_cvt_kernel<<<dim3(H_ / 32, D_ / 32, E_), tb, 0, stream>>>(w1, w1t, D_, H_);
  cvt_x_kernel<<<2048, 256, 0, stream>>>(x, xb, (int)(xN / 4));

  // GEMM1: 128² tiles -> 4096 blocks, 2 blocks/CU
  gemm_mlp1<<<E_ * 16 * 32, 256, 0, stream>>>(xb, w1t, b1, hb);
  // GEMM2: 256² tiles -> 256 blocks
  gemm_mlp2<<<E_ * 8 * (D_ / 256), 512, 0, stream>>>(hb, w2t, b2, out);
}

// Round 12
// 433.985 us; speedup vs baseline: 1.0662x; 1.0662x over previous
//
#include <hip/hip_runtime.h>
#include <stdint.h>

#define B_ 2
#define E_ 8
#define N_ 1024
#define D_ 1024
#define H_ 4096

typedef float f32x4 __attribute__((ext_vector_type(4)));
typedef __bf16 bf16x8 __attribute__((ext_vector_type(8)));
typedef __attribute__((address_space(3))) const unsigned short lds_cus;

__device__ __forceinline__ unsigned short f2bf(float f) {
  union { float f; uint32_t u; } v; v.f = f;
  uint32_t u = v.u;
  return (unsigned short)((u + 0x7FFFu + ((u >> 16) & 1u)) >> 16);  // RNE
}

// tanh-form GELU (max |delta| vs exact erf-GELU ~1e-3, inside threshold headroom)
__device__ __forceinline__ float gelu_fast(float x) {
  float x3 = x * x * x;
  float y = 0.79788456080286536f * (x + 0.044715f * x3);
  float e = __expf(2.0f * y);
  float t = 1.0f - 2.0f / (e + 1.0f);   // tanh(y)
  return 0.5f * x * (1.0f + t);
}

__device__ __forceinline__ void gload_lds16(const unsigned short* g, unsigned short* l) {
  __builtin_amdgcn_global_load_lds(
      (__attribute__((address_space(1))) void*)g,
      (__attribute__((address_space(3))) void*)l,
      16, 0, 0);
}

__device__ __forceinline__ bf16x8 lds_read_b128(lds_cus* p) {
  bf16x8 r;
  asm volatile("ds_read_b128 %0, %1" : "=v"(r) : "v"(p));
  return r;
}

// ---- elementwise fp32 -> bf16 convert (x) ----
__global__ void cvt_x_kernel(const float* __restrict__ in, unsigned short* __restrict__ out, int n4) {
  int idx = blockIdx.x * blockDim.x + threadIdx.x;
  int stride = gridDim.x * blockDim.x;
  const float4* in4 = (const float4*)in;
  ushort4* out4 = (ushort4*)out;
  for (int i = idx; i < n4; i += stride) {
    float4 f = in4[i];
    ushort4 o;
    o.x = f2bf(f.x); o.y = f2bf(f.y); o.z = f2bf(f.z); o.w = f2bf(f.w);
    out4[i] = o;
  }
}

// ---- tiled transpose + convert: in fp32 [R][C] per expert -> out bf16 [C][R] ----
__global__ void transpose_cvt_kernel(const float* __restrict__ in, unsigned short* __restrict__ out,
                                     int R, int C) {
  __shared__ float tile[32][33];
  const size_t eoff = (size_t)blockIdx.z * R * C;
  const float* src = in + eoff;
  unsigned short* dst = out + eoff;
  const int c0 = blockIdx.x * 32, r0 = blockIdx.y * 32;
  const int tx = threadIdx.x, ty = threadIdx.y;
#pragma unroll
  for (int i = 0; i < 4; ++i)
    tile[ty + 8 * i][tx] = src[(size_t)(r0 + ty + 8 * i) * C + c0 + tx];
  __syncthreads();
#pragma unroll
  for (int i = 0; i < 4; ++i)
    dst[(size_t)(c0 + ty + 8 * i) * R + r0 + tx] = f2bf(tile[tx][ty + 8 * i]);
}

// ============================================================================
// Shared GEMM body — EXACTLY G2's proven structure for both GEMMs:
// 256x256 tile, BK=64, 8 waves, 4-phase/K-tile, named 128KB LDS, counted
// vmcnt(4), asm ds_read + lgkm(0)+sched_barrier, setprio, T1 swizzle.
// One output tile per block (no NTG loop). G2 measured AT its LDS-read
// roofline (816 cyc/phase vs 768 bound) — this round tests whether G1
// (K=1024, 1024 blocks, 4 rounds/CU) inherits that per-phase rate.
// ============================================================================
template <int K, int NCOLS, bool GELU>
__device__ __forceinline__ void gemm_body(const unsigned short* __restrict__ A,
                                          const unsigned short* __restrict__ Bt,
                                          const float* __restrict__ bias,
                                          unsigned short* __restrict__ OutBf,
                                          float* __restrict__ OutF) {
  constexpr int MT = 2048 / 256;
  constexpr int NTL = NCOLS / 256;
  constexpr int NT = K / 64;

  __shared__ __align__(16) unsigned short A0k0[8192], A0k1[8192], B0k0[8192], B0k1[8192];
  __shared__ __align__(16) unsigned short A1k0[8192], A1k1[8192], B1k0[8192], B1k1[8192];

  const int nwg = gridDim.x;
  const int flat = blockIdx.x;
  const int swz = (flat & 7) * (nwg >> 3) + (flat >> 3);
  const int e = swz / (MT * NTL);
  const int rem = swz - e * (MT * NTL);
  const int nt = rem / MT;
  const int mt = rem - nt * MT;

  const int m0 = mt * 256;
  const int b = m0 >> 10;
  const int nl = m0 & 1023;
  const size_t arow0 = (size_t)((b * E_ + e) * N_ + nl);
  const int n0 = nt * 256;

  const unsigned short* Ab = A + arow0 * K;
  const unsigned short* Bb = Bt + ((size_t)e * NCOLS + n0) * K;

  const int tid = threadIdx.x;
  const int w = tid >> 6;
  const int lane = tid & 63;
  const int wr = w >> 2;
  const int wc = w & 3;
  const int fr = lane & 15;
  const int kg = lane >> 4;
  const int sxor = kg ^ ((lane >> 1) & 3);

  const int scol = (((lane & 3) ^ ((lane >> 3) & 3)) << 3);
  const int srow0 = w * 32 + (lane >> 2);
  const int srow1 = srow0 + 16;
  const unsigned short* aS0 = Ab + (size_t)srow0 * K + scol;
  const unsigned short* aS1 = Ab + (size_t)srow1 * K + scol;
  const unsigned short* bS0 = Bb + (size_t)srow0 * K + scol;
  const unsigned short* bS1 = Bb + (size_t)srow1 * K + scol;

  const int aBase = (wr * 128 + fr) * 32 + sxor * 8;
  const int bBase = (wc * 64 + fr) * 32 + sxor * 8;
  const int rb = kg * 4;

#define STAGE(ARR, S0_, S1_, t, kh) do {                           \
    const size_t ko_ = (size_t)(t) * 64 + (kh) * 32;               \
    gload_lds16(S0_ + ko_, &ARR[w * 1024]);                        \
    gload_lds16(S1_ + ko_, &ARR[w * 1024 + 512]);                  \
  } while (0)

#define WAIT_LGKM() do {                                                      \
    asm volatile("s_waitcnt lgkmcnt(0)");                                     \
    __builtin_amdgcn_sched_barrier(0);                                        \
  } while (0)

#define MFMA_CLUSTER(ROFF)                                                    \
    __builtin_amdgcn_s_setprio(1);                                            \
    _Pragma("unroll")                                                         \
    for (int mi = 0; mi < 4; ++mi)                                            \
      _Pragma("unroll")                                                       \
      for (int ni = 0; ni < 4; ++ni)                                          \
        acc[(ROFF) + mi][ni] =                                                \
            __builtin_amdgcn_mfma_f32_16x16x32_bf16(av[mi], bv[ni],           \
                                                    acc[(ROFF) + mi][ni], 0, 0, 0); \
    __builtin_amdgcn_s_setprio(0);

#define ITER(t, CA0, CA1, CB0, CB1, NA1, NB1) do {                            \
    bf16x8 av[4], bv[4];                                                      \
    _Pragma("unroll")                                                         \
    for (int i = 0; i < 4; ++i) {                                             \
      av[i] = lds_read_b128((lds_cus*)&CA0[aBase + i * 512]);                 \
      bv[i] = lds_read_b128((lds_cus*)&CB0[bBase + i * 512]);                 \
    }                                                                         \
    if ((t) + 1 < NT) STAGE(NA1, aS0, aS1, (t) + 1, 1);                       \
    __builtin_amdgcn_s_barrier();                                             \
    WAIT_LGKM();                                                              \
    MFMA_CLUSTER(0)                                                           \
    __builtin_amdgcn_s_barrier();                                             \
    _Pragma("unroll")                                                         \
    for (int i = 0; i < 4; ++i)                                               \
      av[i] = lds_read_b128((lds_cus*)&CA0[aBase + 2048 + i * 512]);          \
    if ((t) + 1 < NT) STAGE(NB1, bS0, bS1, (t) + 1, 1);                       \
    __builtin_amdgcn_s_barrier();                                             \
    WAIT_LGKM();                                                              \
    MFMA_CLUSTER(4)                                                           \
    __builtin_amdgcn_s_barrier();                                             \
    _Pragma("unroll")                                                         \
    for (int i = 0; i < 4; ++i) {                                             \
      av[i] = lds_read_b128((lds_cus*)&CA1[aBase + i * 512]);                 \
      bv[i] = lds_read_b128((lds_cus*)&CB1[bBase + i * 512]);                 \
    }                                                                         \
    if ((t) + 2 < NT) STAGE(CA0, aS0, aS1, (t) + 2, 0);                       \
    __builtin_amdgcn_s_barrier();                                             \
    WAIT_LGKM();                                                              \
    MFMA_CLUSTER(0)                                                           \
    __builtin_amdgcn_s_barrier();                                             \
    _Pragma("unroll")                                                         \
    for (int i = 0; i < 4; ++i)                                               \
      av[i] = lds_read_b128((lds_cus*)&CA1[aBase + 2048 + i * 512]);          \
    if ((t) + 2 < NT) STAGE(CB0, bS0, bS1, (t) + 2, 0);                       \
    __builtin_amdgcn_s_barrier();                                             \
    WAIT_LGKM();                                                              \
    MFMA_CLUSTER(4)                                                           \
    if ((t) + 2 < NT) { asm volatile("s_waitcnt vmcnt(4)" ::: "memory"); }    \
    else              { asm volatile("s_waitcnt vmcnt(0)" ::: "memory"); }    \
    __builtin_amdgcn_s_barrier();                                             \
  } while (0)

  f32x4 acc[8][4];
#pragma unroll
  for (int i = 0; i < 8; ++i)
#pragma unroll
    for (int j = 0; j < 4; ++j)
      acc[i][j] = (f32x4){0.f, 0.f, 0.f, 0.f};

  STAGE(A0k0, aS0, aS1, 0, 0); STAGE(B0k0, bS0, bS1, 0, 0);
  STAGE(A0k1, aS0, aS1, 0, 1); STAGE(B0k1, bS0, bS1, 0, 1);
  STAGE(A1k0, aS0, aS1, 1, 0); STAGE(B1k0, bS0, bS1, 1, 0);
  asm volatile("s_waitcnt vmcnt(4)" ::: "memory");
  __builtin_amdgcn_s_barrier();

#pragma unroll 1
  for (int tt = 0; tt < NT; tt += 2) {
    ITER(tt,     A0k0, A0k1, B0k0, B0k1, A1k1, B1k1);
    ITER(tt + 1, A1k0, A1k1, B1k0, B1k1, A0k1, B0k1);
  }

#undef ITER
#undef MFMA_CLUSTER
#undef WAIT_LGKM
#undef STAGE

  // epilogue: C/D layout col=lane&15, row=(lane>>4)*4+j
  if constexpr (GELU) {
    // ni-inner nontemporal bf16 stores (R7 order + R11 NT hint)
    float bval[4];
#pragma unroll
    for (int ni = 0; ni < 4; ++ni)
      bval[ni] = bias[(size_t)e * NCOLS + n0 + wc * 64 + ni * 16 + fr];
    const size_t gcb = (size_t)n0 + wc * 64 + fr;
#pragma unroll
    for (int MI = 0; MI < 8; ++MI) {
#pragma unroll
      for (int j = 0; j < 4; ++j) {
        const size_t orow = arow0 + (size_t)(wr * 128 + MI * 16 + rb + j);
        unsigned short* rp = OutBf + orow * NCOLS + gcb;
#pragma unroll
        for (int ni = 0; ni < 4; ++ni)
          __builtin_nontemporal_store(f2bf(gelu_fast(acc[MI][ni][j] + bval[ni])),
                                      &rp[ni * 16]);
      }
    }
  } else {
#pragma unroll
    for (int ni = 0; ni < 4; ++ni) {
      const int gc = n0 + wc * 64 + ni * 16 + fr;
      const float bval = bias[(size_t)e * NCOLS + gc];
#pragma unroll
      for (int MI = 0; MI < 8; ++MI) {
        const size_t orow = arow0 + (size_t)(wr * 128 + MI * 16 + rb);
#pragma unroll
        for (int j = 0; j < 4; ++j)
          __builtin_nontemporal_store(acc[MI][ni][j] + bval,
                                      &OutF[(orow + j) * NCOLS + gc]);
      }
    }
  }
}

__global__ __launch_bounds__(512, 2)
void gemm_mlp1(const unsigned short* __restrict__ A, const unsigned short* __restrict__ Bt,
               const float* __restrict__ bias, unsigned short* __restrict__ OutBf) {
  gemm_body<D_, H_, true>(A, Bt, bias, OutBf, nullptr);
}

__global__ __launch_bounds__(512, 2)
void gemm_mlp2(const unsigned short* __restrict__ A, const unsigned short* __restrict__ Bt,
               const float* __restrict__ bias, float* __restrict__ OutF) {
  gemm_body<H_, D_, false>(A, Bt, bias, nullptr, OutF);
}

extern "C" void kernel_launch(void* const* d_in, const int* in_sizes, int n_in,
                              void* d_out, int out_size, void* d_ws, size_t ws_size,
                              hipStream_t stream) {
  const float* x  = (const float*)d_in[0];
  const float* w1 = (const float*)d_in[1];
  const float* b1 = (const float*)d_in[2];
  const float* w2 = (const float*)d_in[3];
  const float* b2 = (const float*)d_in[4];
  float* out = (float*)d_out;

  const size_t xN  = (size_t)B_ * E_ * N_ * D_;
  const size_t w1N = (size_t)E_ * D_ * H_;
  const size_t w2N = (size_t)E_ * H_ * D_;
  const size_t hN  = (size_t)B_ * E_ * N_ * H_;
  const size_t needed = (xN + w1N + w2N + hN) * 2;
  if (ws_size < needed) return;

  unsigned short* xb  = (unsigned short*)d_ws;
  unsigned short* w1t = xb + xN;   // [E][H][D] bf16
  unsigned short* w2t = w1t + w1N; // [E][D][H] bf16
  unsigned short* hb  = w2t + w2N; // [B][E][N][H] bf16

  dim3 tb(32, 8);
  transpose_cvt_kernel<<<dim3(D_ / 32, H_ / 32, E_), tb, 0, stream>>>(w2, w2t, H_, D_);
  transpose_cvt_kernel<<<dim3(H_ / 32, D_ / 32, E_), tb, 0, stream>>>(w1, w1t, D_, H_);
  cvt_x_kernel<<<2048, 256, 0, stream>>>(x, xb, (int)(xN / 4));

  // GEMM1: G2-clone structure; 8e x 8mt x 16nt = 1024 blocks (4 rounds/CU)
  gemm_mlp1<<<E_ * 8 * (H_ / 256), 512, 0, stream>>>(xb, w1t, b1, hb);
  // GEMM2: 256 blocks (1 round/CU)
  gemm_mlp2<<<E_ * 8 * (D_ / 256), 512, 0, stream>>>(hb, w2t, b2, out);
}

// Round 13
// 425.120 us; speedup vs baseline: 1.0885x; 1.0209x over previous
//
#include <hip/hip_runtime.h>
#include <stdint.h>

#define B_ 2
#define E_ 8
#define N_ 1024
#define D_ 1024
#define H_ 4096

typedef float f32x4 __attribute__((ext_vector_type(4)));
typedef __bf16 bf16x8 __attribute__((ext_vector_type(8)));
typedef __attribute__((address_space(3))) const unsigned short lds_cus;

__device__ __forceinline__ unsigned short f2bf(float f) {
  union { float f; uint32_t u; } v; v.f = f;
  uint32_t u = v.u;
  return (unsigned short)((u + 0x7FFFu + ((u >> 16) & 1u)) >> 16);  // RNE
}

// tanh-form GELU (max |delta| vs exact erf-GELU ~1e-3, inside threshold headroom)
__device__ __forceinline__ float gelu_fast(float x) {
  float x3 = x * x * x;
  float y = 0.79788456080286536f * (x + 0.044715f * x3);
  float e = __expf(2.0f * y);
  float t = 1.0f - 2.0f / (e + 1.0f);   // tanh(y)
  return 0.5f * x * (1.0f + t);
}

__device__ __forceinline__ void gload_lds16(const unsigned short* g, unsigned short* l) {
  __builtin_amdgcn_global_load_lds(
      (__attribute__((address_space(1))) void*)g,
      (__attribute__((address_space(3))) void*)l,
      16, 0, 0);
}

__device__ __forceinline__ bf16x8 lds_read_b128(lds_cus* p) {
  bf16x8 r;
  asm volatile("ds_read_b128 %0, %1" : "=v"(r) : "v"(p));
  return r;
}

// ---- elementwise fp32 -> bf16 convert (x) ----
__global__ void cvt_x_kernel(const float* __restrict__ in, unsigned short* __restrict__ out, int n4) {
  int idx = blockIdx.x * blockDim.x + threadIdx.x;
  int stride = gridDim.x * blockDim.x;
  const float4* in4 = (const float4*)in;
  ushort4* out4 = (ushort4*)out;
  for (int i = idx; i < n4; i += stride) {
    float4 f = in4[i];
    ushort4 o;
    o.x = f2bf(f.x); o.y = f2bf(f.y); o.z = f2bf(f.z); o.w = f2bf(f.w);
    out4[i] = o;
  }
}

// ---- tiled transpose + convert: in fp32 [R][C] per expert -> out bf16 [C][R] ----
__global__ void transpose_cvt_kernel(const float* __restrict__ in, unsigned short* __restrict__ out,
                                     int R, int C) {
  __shared__ float tile[32][33];
  const size_t eoff = (size_t)blockIdx.z * R * C;
  const float* src = in + eoff;
  unsigned short* dst = out + eoff;
  const int c0 = blockIdx.x * 32, r0 = blockIdx.y * 32;
  const int tx = threadIdx.x, ty = threadIdx.y;
#pragma unroll
  for (int i = 0; i < 4; ++i)
    tile[ty + 8 * i][tx] = src[(size_t)(r0 + ty + 8 * i) * C + c0 + tx];
  __syncthreads();
#pragma unroll
  for (int i = 0; i < 4; ++i)
    dst[(size_t)(c0 + ty + 8 * i) * R + r0 + tx] = f2bf(tile[tx][ty + 8 * i]);
}

// ============================================================================
// GEMM1 (R13): the m97/R1 skeleton at HIGH CO-RESIDENCY + T2 swizzle.
// 128x128 tile, BK=64, 4 waves (2x2), SINGLE-buffered 32KB LDS -> 5 blocks/CU.
// Simple drain-0 2-barrier K-loop (compiler-managed waits; correct by
// construction). Multi-block overlap (m114) hides the barrier drains and the
// end-of-block store drains -- the ingredient every G1 variant since R2
// lacked (all ran at <=2 blocks/CU).
// T2: 8-slot XOR swizzle, phys_slot = logical_slot ^ ((row>>1)&7): staging
// pre-swizzles the global k-offset (LDS dest stays linear, rule #21); reads
// use slot = (kg | (kh<<2)) ^ ((fr>>1)&7). 2-way residual conflicts = free.
// Epilogue: ni-inner plain bf16 scalar stores (R7/R10-proven, WRITE=ideal).
// ============================================================================
__global__ __launch_bounds__(256, 4)
void gemm_mlp1(const unsigned short* __restrict__ A,     // xb  [16384][1024]
               const unsigned short* __restrict__ Bt,    // w1t [E][4096][1024]
               const float* __restrict__ bias,           // b1  [E][4096]
               unsigned short* __restrict__ Out) {       // hb  [16384][4096]
  constexpr int K = D_;        // 1024
  constexpr int NCOLS = H_;    // 4096
  constexpr int NT = K / 64;   // 16
  constexpr int MT = 16;       // 2048/128 m-tiles per expert
  constexpr int NTL = 32;      // 4096/128 n-tiles per expert

  __shared__ __align__(16) unsigned short Alds[8192];    // [128 rows][8 slots of 8]
  __shared__ __align__(16) unsigned short Blds[8192];

  const int nwg = gridDim.x;               // 4096, %8==0
  const int flat = blockIdx.x;
  const int swz = (flat & 7) * (nwg >> 3) + (flat >> 3);
  const int e = swz / (MT * NTL);
  const int rem = swz - e * (MT * NTL);
  const int nt = rem >> 4;                 // / MT
  const int mt = rem & 15;

  const int m0 = mt * 128;
  const int b = m0 >> 10;
  const int nl = m0 & 1023;
  const size_t arow0 = (size_t)((b * E_ + e) * N_ + nl);
  const int n0 = nt * 128;

  const int tid = threadIdx.x;
  const int wid = tid >> 6;                // 0..3
  const int lane = tid & 63;
  const int wr = wid >> 1, wc = wid & 1;   // 64-row / 64-col halves
  const int fr = lane & 15;
  const int kg = lane >> 4;                // 0..3

  // ---- staging addressing (pre-swizzled source, linear LDS dest) ----
  // chunk c = wid*4+j covers rows c*8..c*8+7; lane: row lr=lane>>3, slot sl=lane&7.
  // dest elem = c*512 + lane*8 (wave-uniform base &lds[c*512], lane x 16B).
  // source k-slot = sl ^ ((grow>>1)&7)  [phys slot sl holds logical sl^f].
  const int lr = lane >> 3;
  const int sl = lane & 7;
  const unsigned short* aSrc[4];
  const unsigned short* bSrc[4];
  unsigned short* aDst[4];
  unsigned short* bDst[4];
#pragma unroll
  for (int j = 0; j < 4; ++j) {
    const int c = wid * 4 + j;
    const int grow = c * 8 + lr;
    const int f = (grow >> 1) & 7;
    const int ksl = (sl ^ f) << 3;
    aSrc[j] = A + (arow0 + grow) * K + ksl;
    bSrc[j] = Bt + ((size_t)e * NCOLS + n0 + grow) * K + ksl;
    aDst[j] = &Alds[c * 512];
    bDst[j] = &Blds[c * 512];
  }

  // ---- fragment-read addressing ----
  // row = (half*64 + i*16 + fr); (row>>1)&7 = (fr>>1)&7 (i*16>>1 = 8i == 0 mod 8).
  // logical slot = kh*4 + kg (kh in {0,1}); phys = (kh*4 + kg) ^ f_r
  //             = (kg ^ f_r) ^ (kh*4)   [4|kg bit-disjoint].
  const int f_r = (fr >> 1) & 7;
  const int slot0 = kg ^ f_r;              // kh=0 phys slot
  const int aRow = (wr * 64 + fr) * 64;
  const int bRow = (wc * 64 + fr) * 64;
  const int rb = kg * 4;

  f32x4 acc[4][4];
#pragma unroll
  for (int i = 0; i < 4; ++i)
#pragma unroll
    for (int j = 0; j < 4; ++j)
      acc[i][j] = (f32x4){0.f, 0.f, 0.f, 0.f};

#pragma unroll 1
  for (int t = 0; t < NT; ++t) {
    __syncthreads();  // previous tile's reads done before LDS overwrite
#pragma unroll
    for (int j = 0; j < 4; ++j) {
      gload_lds16(aSrc[j] + t * 64, aDst[j]);
      gload_lds16(bSrc[j] + t * 64, bDst[j]);
    }
    __syncthreads();  // compiler drains vmcnt(0): staged tile visible
#pragma unroll
    for (int kh = 0; kh < 2; ++kh) {
      const int sx = (slot0 ^ (kh << 2)) << 3;
      bf16x8 av[4], bv[4];
#pragma unroll
      for (int i = 0; i < 4; ++i) {
        av[i] = *(const bf16x8*)&Alds[aRow + i * 1024 + sx];
        bv[i] = *(const bf16x8*)&Blds[bRow + i * 1024 + sx];
      }
      __builtin_amdgcn_s_setprio(1);
#pragma unroll
      for (int mi = 0; mi < 4; ++mi)
#pragma unroll
        for (int ni = 0; ni < 4; ++ni)
          acc[mi][ni] = __builtin_amdgcn_mfma_f32_16x16x32_bf16(av[mi], bv[ni], acc[mi][ni], 0, 0, 0);
      __builtin_amdgcn_s_setprio(0);
    }
  }

  // epilogue: C/D layout col=lane&15, row=(lane>>4)*4+j; ni-inner plain stores
  float bval[4];
#pragma unroll
  for (int ni = 0; ni < 4; ++ni)
    bval[ni] = bias[(size_t)e * NCOLS + n0 + wc * 64 + ni * 16 + fr];
  const size_t gcb = (size_t)n0 + wc * 64 + fr;
#pragma unroll
  for (int mi = 0; mi < 4; ++mi) {
#pragma unroll
    for (int j = 0; j < 4; ++j) {
      const size_t orow = arow0 + (size_t)(wr * 64 + mi * 16 + rb + j);
      unsigned short* rp = Out + orow * NCOLS + gcb;
#pragma unroll
      for (int ni = 0; ni < 4; ++ni)
        rp[ni * 16] = f2bf(gelu_fast(acc[mi][ni][j] + bval[ni]));
    }
  }
}

// ============================================================================
// GEMM2 (R4-proven structure, plain fp32 stores): 256x256, BK=64, 8 waves,
// 4-phase/K-tile, named 128KB LDS, counted vmcnt(4).
// ============================================================================
__global__ __launch_bounds__(512, 2)
void gemm_mlp2(const unsigned short* __restrict__ A,     // hb  [16384][4096]
               const unsigned short* __restrict__ Bt,    // w2t [E][1024][4096]
               const float* __restrict__ bias,           // b2  [E][1024]
               float* __restrict__ OutF) {               // out [16384][1024]
  constexpr int K = H_;
  constexpr int NCOLS = D_;
  constexpr int NT = K / 64;
  constexpr int MT = 8;
  constexpr int NTL = 4;

  __shared__ __align__(16) unsigned short A0k0[8192], A0k1[8192], B0k0[8192], B0k1[8192];
  __shared__ __align__(16) unsigned short A1k0[8192], A1k1[8192], B1k0[8192], B1k1[8192];

  const int nwg = gridDim.x;
  const int flat = blockIdx.x;
  const int swz = (flat & 7) * (nwg >> 3) + (flat >> 3);
  const int e = swz / (MT * NTL);
  const int rem = swz - e * (MT * NTL);
  const int nt = rem / MT;
  const int mt = rem - nt * MT;

  const int m0 = mt * 256;
  const int b = m0 >> 10;
  const int nl = m0 & 1023;
  const size_t arow0 = (size_t)((b * E_ + e) * N_ + nl);
  const int n0 = nt * 256;

  const unsigned short* Ab = A + arow0 * K;
  const unsigned short* Bb = Bt + ((size_t)e * NCOLS + n0) * K;

  const int tid = threadIdx.x;
  const int w = tid >> 6;
  const int lane = tid & 63;
  const int wr = w >> 2;
  const int wc = w & 3;
  const int fr = lane & 15;
  const int kg = lane >> 4;
  const int sxor = kg ^ ((lane >> 1) & 3);

  const int scol = (((lane & 3) ^ ((lane >> 3) & 3)) << 3);
  const int srow0 = w * 32 + (lane >> 2);
  const int srow1 = srow0 + 16;
  const unsigned short* aS0 = Ab + (size_t)srow0 * K + scol;
  const unsigned short* aS1 = Ab + (size_t)srow1 * K + scol;
  const unsigned short* bS0 = Bb + (size_t)srow0 * K + scol;
  const unsigned short* bS1 = Bb + (size_t)srow1 * K + scol;

  const int aBase = (wr * 128 + fr) * 32 + sxor * 8;
  const int bBase = (wc * 64 + fr) * 32 + sxor * 8;
  const int rb = kg * 4;

#define STAGE(ARR, S0_, S1_, t, kh) do {                           \
    const size_t ko_ = (size_t)(t) * 64 + (kh) * 32;               \
    gload_lds16(S0_ + ko_, &ARR[w * 1024]);                        \
    gload_lds16(S1_ + ko_, &ARR[w * 1024 + 512]);                  \
  } while (0)

#define WAIT_LGKM() do {                                                      \
    asm volatile("s_waitcnt lgkmcnt(0)");                                     \
    __builtin_amdgcn_sched_barrier(0);                                        \
  } while (0)

#define MFMA_CLUSTER(ROFF)                                                    \
    __builtin_amdgcn_s_setprio(1);                                            \
    _Pragma("unroll")                                                         \
    for (int mi = 0; mi < 4; ++mi)                                            \
      _Pragma("unroll")                                                       \
      for (int ni = 0; ni < 4; ++ni)                                          \
        acc[(ROFF) + mi][ni] =                                                \
            __builtin_amdgcn_mfma_f32_16x16x32_bf16(av[mi], bv[ni],           \
                                                    acc[(ROFF) + mi][ni], 0, 0, 0); \
    __builtin_amdgcn_s_setprio(0);

#define ITER(t, CA0, CA1, CB0, CB1, NA1, NB1) do {                            \
    bf16x8 av[4], bv[4];                                                      \
    _Pragma("unroll")                                                         \
    for (int i = 0; i < 4; ++i) {                                             \
      av[i] = lds_read_b128((lds_cus*)&CA0[aBase + i * 512]);                 \
      bv[i] = lds_read_b128((lds_cus*)&CB0[bBase + i * 512]);                 \
    }                                                                         \
    if ((t) + 1 < NT) STAGE(NA1, aS0, aS1, (t) + 1, 1);                       \
    __builtin_amdgcn_s_barrier();                                             \
    WAIT_LGKM();                                                              \
    MFMA_CLUSTER(0)                                                           \
    __builtin_amdgcn_s_barrier();                                             \
    _Pragma("unroll")                                                         \
    for (int i = 0; i < 4; ++i)                                               \
      av[i] = lds_read_b128((lds_cus*)&CA0[aBase + 2048 + i * 512]);          \
    if ((t) + 1 < NT) STAGE(NB1, bS0, bS1, (t) + 1, 1);                       \
    __builtin_amdgcn_s_barrier();                                             \
    WAIT_LGKM();                                                              \
    MFMA_CLUSTER(4)                                                           \
    __builtin_amdgcn_s_barrier();                                             \
    _Pragma("unroll")                                                         \
    for (int i = 0; i < 4; ++i) {                                             \
      av[i] = lds_read_b128((lds_cus*)&CA1[aBase + i * 512]);                 \
      bv[i] = lds_read_b128((lds_cus*)&CB1[bBase + i * 512]);                 \
    }                                                                         \
    if ((t) + 2 < NT) STAGE(CA0, aS0, aS1, (t) + 2, 0);                       \
    __builtin_amdgcn_s_barrier();                                             \
    WAIT_LGKM();                                                              \
    MFMA_CLUSTER(0)                                                           \
    __builtin_amdgcn_s_barrier();                                             \
    _Pragma("unroll")                                                         \
    for (int i = 0; i < 4; ++i)                                               \
      av[i] = lds_read_b128((lds_cus*)&CA1[aBase + 2048 + i * 512]);          \
    if ((t) + 2 < NT) STAGE(CB0, bS0, bS1, (t) + 2, 0);                       \
    __builtin_amdgcn_s_barrier();                                             \
    WAIT_LGKM();                                                              \
    MFMA_CLUSTER(4)                                                           \
    if ((t) + 2 < NT) { asm volatile("s_waitcnt vmcnt(4)" ::: "memory"); }    \
    else              { asm volatile("s_waitcnt vmcnt(0)" ::: "memory"); }    \
    __builtin_amdgcn_s_barrier();                                             \
  } while (0)

  f32x4 acc[8][4];
#pragma unroll
  for (int i = 0; i < 8; ++i)
#pragma unroll
    for (int j = 0; j < 4; ++j)
      acc[i][j] = (f32x4){0.f, 0.f, 0.f, 0.f};

  STAGE(A0k0, aS0, aS1, 0, 0); STAGE(B0k0, bS0, bS1, 0, 0);
  STAGE(A0k1, aS0, aS1, 0, 1); STAGE(B0k1, bS0, bS1, 0, 1);
  STAGE(A1k0, aS0, aS1, 1, 0); STAGE(B1k0, bS0, bS1, 1, 0);
  asm volatile("s_waitcnt vmcnt(4)" ::: "memory");
  __builtin_amdgcn_s_barrier();

#pragma unroll 1
  for (int tt = 0; tt < NT; tt += 2) {
    ITER(tt,     A0k0, A0k1, B0k0, B0k1, A1k1, B1k1);
    ITER(tt + 1, A1k0, A1k1, B1k0, B1k1, A0k1, B0k1);
  }

#undef ITER
#undef MFMA_CLUSTER
#undef WAIT_LGKM
#undef STAGE

#pragma unroll
  for (int ni = 0; ni < 4; ++ni) {
    const int gc = n0 + wc * 64 + ni * 16 + fr;
    const float bval = bias[(size_t)e * NCOLS + gc];
#pragma unroll
    for (int MI = 0; MI < 8; ++MI) {
      const size_t orow = arow0 + (size_t)(wr * 128 + MI * 16 + rb);
#pragma unroll
      for (int j = 0; j < 4; ++j)
        OutF[(orow + j) * NCOLS + gc] = acc[MI][ni][j] + bval;
    }
  }
}

extern "C" void kernel_launch(void* const* d_in, const int* in_sizes, int n_in,
                              void* d_out, int out_size, void* d_ws, size_t ws_size,
                              hipStream_t stream) {
  const float* x  = (const float*)d_in[0];
  const float* w1 = (const float*)d_in[1];
  const float* b1 = (const float*)d_in[2];
  const float* w2 = (const float*)d_in[3];
  const float* b2 = (const float*)d_in[4];
  float* out = (float*)d_out;

  const size_t xN  = (size_t)B_ * E_ * N_ * D_;
  const size_t w1N = (size_t)E_ * D_ * H_;
  const size_t w2N = (size_t)E_ * H_ * D_;
  const size_t hN  = (size_t)B_ * E_ * N_ * H_;
  const size_t needed = (xN + w1N + w2N + hN) * 2;
  if (ws_size < needed) return;

  unsigned short* xb  = (unsigned short*)d_ws;
  unsigned short* w1t = xb + xN;   // [E][H][D] bf16
  unsigned short* w2t = w1t + w1N; // [E][D][H] bf16
  unsigned short* hb  = w2t + w2N; // [B][E][N][H] bf16

  dim3 tb(32, 8);
  transpose_cvt_kernel<<<dim3(D_ / 32, H_ / 32, E_), tb, 0, stream>>>(w2, w2t, H_, D_);
  transpose_cvt_kernel<<<dim3(H_ / 32, D_ / 32, E_), tb, 0, stream>>>(w1, w1t, D_, H_);
  cvt_x_kernel<<<2048, 256, 0, stream>>>(x, xb, (int)(xN / 4));

  // GEMM1: 128² tiles, 32KB LDS -> 8e x 16mt x 32nt = 4096 blocks, 5 blocks/CU
  gemm_mlp1<<<E_ * 16 * 32, 256, 0, stream>>>(xb, w1t, b1, hb);
  // GEMM2: 256² tiles -> 256 blocks
  gemm_mlp2<<<E_ * 8 * (D_ / 256), 512, 0, stream>>>(hb, w2t, b2, out);
}

// Round 14
// 408.296 us; speedup vs baseline: 1.1333x; 1.0412x over previous
//
#include <hip/hip_runtime.h>
#include <stdint.h>

#define B_ 2
#define E_ 8
#define N_ 1024
#define D_ 1024
#define H_ 4096

typedef float f32x4 __attribute__((ext_vector_type(4)));
typedef __bf16 bf16x8 __attribute__((ext_vector_type(8)));
typedef __attribute__((address_space(3))) const unsigned short lds_cus;

__device__ __forceinline__ unsigned short f2bfu(float f) {
  __bf16 b = (__bf16)f;                      // native v_cvt, RNE
  return __builtin_bit_cast(unsigned short, b);
}

// tanh-form GELU, exp2-folded: g = x*E/(E+1), E = 2^(c1*x + c2*x^3),
// c1 = 2*0.79788456*log2(e), c2 = c1*0.044715. ~7 VALU incl 1 transcendental.
__device__ __forceinline__ float gelu_fast(float x) {
  float u = x * x;
  float y = x * __builtin_fmaf(0.1029432f, u, 2.3022074f);
  float e = __builtin_exp2f(y);
  float r = __builtin_amdgcn_rcpf(e + 1.0f);
  return x - x * r;
}

__device__ __forceinline__ void gload_lds16(const unsigned short* g, unsigned short* l) {
  __builtin_amdgcn_global_load_lds(
      (__attribute__((address_space(1))) void*)g,
      (__attribute__((address_space(3))) void*)l,
      16, 0, 0);
}

__device__ __forceinline__ bf16x8 lds_read_b128(lds_cus* p) {
  bf16x8 r;
  asm volatile("ds_read_b128 %0, %1" : "=v"(r) : "v"(p));
  return r;
}

// ============================================================================
// Fused conversion kernel: one launch covers
//   job A: w2 [E][H][D] -> w2t [E][D][H]   (8192 tile-blocks)
//   job B: w1 [E][D][H] -> w1t [E][H][D]   (8192 tile-blocks)
//   job C: x fp32 -> xb bf16               (2048 grid-stride blocks)
// 64x64 transpose tiles: float4 loads (16B/lane), ushort4 stores (8B/lane,
// 128B contiguous per 16-lane group). LDS [64][65] f32, 2-way conflicts max.
// ============================================================================
#define W2T_BLOCKS ((H_ / 64) * (D_ / 64) * E_)   // 8192
#define W1T_BLOCKS ((D_ / 64) * (H_ / 64) * E_)   // 8192
#define CVT_BLOCKS 2048

__device__ __forceinline__ void transpose64(const float* __restrict__ src,
                                            unsigned short* __restrict__ dst,
                                            int R, int C, int jid, float (*tile)[65]) {
  const int tpe = (R >> 6) * (C >> 6);
  const int e = jid / tpe;
  const int rem = jid - e * tpe;
  const int ntc = C >> 6;
  const int tr = rem / ntc;
  const int tc = rem - tr * ntc;
  src += (size_t)e * R * C;
  dst += (size_t)e * R * C;
  const int r0 = tr << 6, c0 = tc << 6;

  const int tid = threadIdx.x;
  const int lr = tid >> 4;          // 0..15
  const int lc4 = (tid & 15) << 2;  // 0,4,..,60
#pragma unroll
  for (int i = 0; i < 4; ++i) {
    const float4 v = *(const float4*)&src[(size_t)(r0 + lr + i * 16) * C + c0 + lc4];
    tile[lr + i * 16][lc4 + 0] = v.x;
    tile[lr + i * 16][lc4 + 1] = v.y;
    tile[lr + i * 16][lc4 + 2] = v.z;
    tile[lr + i * 16][lc4 + 3] = v.w;
  }
  __syncthreads();
  const int wr4 = (tid & 15) << 2;  // 0..60 (r-offset)
  const int wc = tid >> 4;          // 0..15 (col group base)
#pragma unroll
  for (int p = 0; p < 4; ++p) {
    const int c = wc + p * 16;
    ushort4 o;
    o.x = f2bfu(tile[wr4 + 0][c]);
    o.y = f2bfu(tile[wr4 + 1][c]);
    o.z = f2bfu(tile[wr4 + 2][c]);
    o.w = f2bfu(tile[wr4 + 3][c]);
    *(ushort4*)&dst[(size_t)(c0 + c) * R + r0 + wr4] = o;
  }
}

__global__ __launch_bounds__(256)
void fused_cvt(const float* __restrict__ w2, const float* __restrict__ w1,
               const float* __restrict__ x,
               unsigned short* __restrict__ w2t, unsigned short* __restrict__ w1t,
               unsigned short* __restrict__ xb, int n4) {
  __shared__ float tile[64][65];
  const int bid = blockIdx.x;
  if (bid < W2T_BLOCKS) {
    transpose64(w2, w2t, H_, D_, bid, tile);                 // [H][D] -> [D][H]
  } else if (bid < W2T_BLOCKS + W1T_BLOCKS) {
    transpose64(w1, w1t, D_, H_, bid - W2T_BLOCKS, tile);    // [D][H] -> [H][D]
  } else {
    const int cb = bid - W2T_BLOCKS - W1T_BLOCKS;
    int idx = cb * 256 + threadIdx.x;
    const int stride = CVT_BLOCKS * 256;
    const float4* in4 = (const float4*)x;
    ushort4* out4 = (ushort4*)xb;
    for (int i = idx; i < n4; i += stride) {
      float4 f = in4[i];
      ushort4 o;
      o.x = f2bfu(f.x); o.y = f2bfu(f.y); o.z = f2bfu(f.z); o.w = f2bfu(f.w);
      out4[i] = o;
    }
  }
}

// ============================================================================
// GEMM1 (R13 structure, frozen): 128x128, BK=64, 4 waves, single-buffered
// 32KB LDS -> 5 blocks/CU co-residency; T2 8-slot XOR swizzle; drain-0 loop.
// Epilogue: ni-inner bf16 stores with exp2-gelu + native cvt (R14 trim).
// ============================================================================
__global__ __launch_bounds__(256, 4)
void gemm_mlp1(const unsigned short* __restrict__ A,     // xb  [16384][1024]
               const unsigned short* __restrict__ Bt,    // w1t [E][4096][1024]
               const float* __restrict__ bias,           // b1  [E][4096]
               unsigned short* __restrict__ Out) {       // hb  [16384][4096]
  constexpr int K = D_;
  constexpr int NCOLS = H_;
  constexpr int NT = K / 64;
  constexpr int MT = 16;
  constexpr int NTL = 32;

  __shared__ __align__(16) unsigned short Alds[8192];
  __shared__ __align__(16) unsigned short Blds[8192];

  const int nwg = gridDim.x;
  const int flat = blockIdx.x;
  const int swz = (flat & 7) * (nwg >> 3) + (flat >> 3);
  const int e = swz / (MT * NTL);
  const int rem = swz - e * (MT * NTL);
  const int nt = rem >> 4;
  const int mt = rem & 15;

  const int m0 = mt * 128;
  const int b = m0 >> 10;
  const int nl = m0 & 1023;
  const size_t arow0 = (size_t)((b * E_ + e) * N_ + nl);
  const int n0 = nt * 128;

  const int tid = threadIdx.x;
  const int wid = tid >> 6;
  const int lane = tid & 63;
  const int wr = wid >> 1, wc = wid & 1;
  const int fr = lane & 15;
  const int kg = lane >> 4;

  const int lr = lane >> 3;
  const int sl = lane & 7;
  const unsigned short* aSrc[4];
  const unsigned short* bSrc[4];
  unsigned short* aDst[4];
  unsigned short* bDst[4];
#pragma unroll
  for (int j = 0; j < 4; ++j) {
    const int c = wid * 4 + j;
    const int grow = c * 8 + lr;
    const int f = (grow >> 1) & 7;
    const int ksl = (sl ^ f) << 3;
    aSrc[j] = A + (arow0 + grow) * K + ksl;
    bSrc[j] = Bt + ((size_t)e * NCOLS + n0 + grow) * K + ksl;
    aDst[j] = &Alds[c * 512];
    bDst[j] = &Blds[c * 512];
  }

  const int f_r = (fr >> 1) & 7;
  const int slot0 = kg ^ f_r;
  const int aRow = (wr * 64 + fr) * 64;
  const int bRow = (wc * 64 + fr) * 64;
  const int rb = kg * 4;

  f32x4 acc[4][4];
#pragma unroll
  for (int i = 0; i < 4; ++i)
#pragma unroll
    for (int j = 0; j < 4; ++j)
      acc[i][j] = (f32x4){0.f, 0.f, 0.f, 0.f};

#pragma unroll 1
  for (int t = 0; t < NT; ++t) {
    __syncthreads();
#pragma unroll
    for (int j = 0; j < 4; ++j) {
      gload_lds16(aSrc[j] + t * 64, aDst[j]);
      gload_lds16(bSrc[j] + t * 64, bDst[j]);
    }
    __syncthreads();
#pragma unroll
    for (int kh = 0; kh < 2; ++kh) {
      const int sx = (slot0 ^ (kh << 2)) << 3;
      bf16x8 av[4], bv[4];
#pragma unroll
      for (int i = 0; i < 4; ++i) {
        av[i] = *(const bf16x8*)&Alds[aRow + i * 1024 + sx];
        bv[i] = *(const bf16x8*)&Blds[bRow + i * 1024 + sx];
      }
      __builtin_amdgcn_s_setprio(1);
#pragma unroll
      for (int mi = 0; mi < 4; ++mi)
#pragma unroll
        for (int ni = 0; ni < 4; ++ni)
          acc[mi][ni] = __builtin_amdgcn_mfma_f32_16x16x32_bf16(av[mi], bv[ni], acc[mi][ni], 0, 0, 0);
      __builtin_amdgcn_s_setprio(0);
    }
  }

  float bval[4];
#pragma unroll
  for (int ni = 0; ni < 4; ++ni)
    bval[ni] = bias[(size_t)e * NCOLS + n0 + wc * 64 + ni * 16 + fr];
  const size_t gcb = (size_t)n0 + wc * 64 + fr;
#pragma unroll
  for (int mi = 0; mi < 4; ++mi) {
#pragma unroll
    for (int j = 0; j < 4; ++j) {
      const size_t orow = arow0 + (size_t)(wr * 64 + mi * 16 + rb + j);
      unsigned short* rp = Out + orow * NCOLS + gcb;
#pragma unroll
      for (int ni = 0; ni < 4; ++ni)
        rp[ni * 16] = f2bfu(gelu_fast(acc[mi][ni][j] + bval[ni]));
    }
  }
}

// ============================================================================
// GEMM2 (R4-proven structure, frozen): 256x256, BK=64, 8 waves, 4-phase/K-tile,
// named 128KB LDS, counted vmcnt(4), plain fp32 stores.
// ============================================================================
__global__ __launch_bounds__(512, 2)
void gemm_mlp2(const unsigned short* __restrict__ A,     // hb  [16384][4096]
               const unsigned short* __restrict__ Bt,    // w2t [E][1024][4096]
               const float* __restrict__ bias,           // b2  [E][1024]
               float* __restrict__ OutF) {               // out [16384][1024]
  constexpr int K = H_;
  constexpr int NCOLS = D_;
  constexpr int NT = K / 64;
  constexpr int MT = 8;
  constexpr int NTL = 4;

  __shared__ __align__(16) unsigned short A0k0[8192], A0k1[8192], B0k0[8192], B0k1[8192];
  __shared__ __align__(16) unsigned short A1k0[8192], A1k1[8192], B1k0[8192], B1k1[8192];

  const int nwg = gridDim.x;
  const int flat = blockIdx.x;
  const int swz = (flat & 7) * (nwg >> 3) + (flat >> 3);
  const int e = swz / (MT * NTL);
  const int rem = swz - e * (MT * NTL);
  const int nt = rem / MT;
  const int mt = rem - nt * MT;

  const int m0 = mt * 256;
  const int b = m0 >> 10;
  const int nl = m0 & 1023;
  const size_t arow0 = (size_t)((b * E_ + e) * N_ + nl);
  const int n0 = nt * 256;

  const unsigned short* Ab = A + arow0 * K;
  const unsigned short* Bb = Bt + ((size_t)e * NCOLS + n0) * K;

  const int tid = threadIdx.x;
  const int w = tid >> 6;
  const int lane = tid & 63;
  const int wr = w >> 2;
  const int wc = w & 3;
  const int fr = lane & 15;
  const int kg = lane >> 4;
  const int sxor = kg ^ ((lane >> 1) & 3);

  const int scol = (((lane & 3) ^ ((lane >> 3) & 3)) << 3);
  const int srow0 = w * 32 + (lane >> 2);
  const int srow1 = srow0 + 16;
  const unsigned short* aS0 = Ab + (size_t)srow0 * K + scol;
  const unsigned short* aS1 = Ab + (size_t)srow1 * K + scol;
  const unsigned short* bS0 = Bb + (size_t)srow0 * K + scol;
  const unsigned short* bS1 = Bb + (size_t)srow1 * K + scol;

  const int aBase = (wr * 128 + fr) * 32 + sxor * 8;
  const int bBase = (wc * 64 + fr) * 32 + sxor * 8;
  const int rb = kg * 4;

#define STAGE(ARR, S0_, S1_, t, kh) do {                           \
    const size_t ko_ = (size_t)(t) * 64 + (kh) * 32;               \
    gload_lds16(S0_ + ko_, &ARR[w * 1024]);                        \
    gload_lds16(S1_ + ko_, &ARR[w * 1024 + 512]);                  \
  } while (0)

#define WAIT_LGKM() do {                                                      \
    asm volatile("s_waitcnt lgkmcnt(0)");                                     \
    __builtin_amdgcn_sched_barrier(0);                                        \
  } while (0)

#define MFMA_CLUSTER(ROFF)                                                    \
    __builtin_amdgcn_s_setprio(1);                                            \
    _Pragma("unroll")                                                         \
    for (int mi = 0; mi < 4; ++mi)                                            \
      _Pragma("unroll")                                                       \
      for (int ni = 0; ni < 4; ++ni)                                          \
        acc[(ROFF) + mi][ni] =                                                \
            __builtin_amdgcn_mfma_f32_16x16x32_bf16(av[mi], bv[ni],           \
                                                    acc[(ROFF) + mi][ni], 0, 0, 0); \
    __builtin_amdgcn_s_setprio(0);

#define ITER(t, CA0, CA1, CB0, CB1, NA1, NB1) do {                            \
    bf16x8 av[4], bv[4];                                                      \
    _Pragma("unroll")                                                         \
    for (int i = 0; i < 4; ++i) {                                             \
      av[i] = lds_read_b128((lds_cus*)&CA0[aBase + i * 512]);                 \
      bv[i] = lds_read_b128((lds_cus*)&CB0[bBase + i * 512]);                 \
    }                                                                         \
    if ((t) + 1 < NT) STAGE(NA1, aS0, aS1, (t) + 1, 1);                       \
    __builtin_amdgcn_s_barrier();                                             \
    WAIT_LGKM();                                                              \
    MFMA_CLUSTER(0)                                                           \
    __builtin_amdgcn_s_barrier();                                             \
    _Pragma("unroll")                                                         \
    for (int i = 0; i < 4; ++i)                                               \
      av[i] = lds_read_b128((lds_cus*)&CA0[aBase + 2048 + i * 512]);          \
    if ((t) + 1 < NT) STAGE(NB1, bS0, bS1, (t) + 1, 1);                       \
    __builtin_amdgcn_s_barrier();                                             \
    WAIT_LGKM();                                                              \
    MFMA_CLUSTER(4)                                                           \
    __builtin_amdgcn_s_barrier();                                             \
    _Pragma("unroll")                                                         \
    for (int i = 0; i < 4; ++i) {                                             \
      av[i] = lds_read_b128((lds_cus*)&CA1[aBase + i * 512]);                 \
      bv[i] = lds_read_b128((lds_cus*)&CB1[bBase + i * 512]);                 \
    }                                                                         \
    if ((t) + 2 < NT) STAGE(CA0, aS0, aS1, (t) + 2, 0);                       \
    __builtin_amdgcn_s_barrier();                                             \
    WAIT_LGKM();                                                              \
    MFMA_CLUSTER(0)                                                           \
    __builtin_amdgcn_s_barrier();                                             \
    _Pragma("unroll")                                                         \
    for (int i = 0; i < 4; ++i)                                               \
      av[i] = lds_read_b128((lds_cus*)&CA1[aBase + 2048 + i * 512]);          \
    if ((t) + 2 < NT) STAGE(CB0, bS0, bS1, (t) + 2, 0);                       \
    __builtin_amdgcn_s_barrier();                                             \
    WAIT_LGKM();                                                              \
    MFMA_CLUSTER(4)                                                           \
    if ((t) + 2 < NT) { asm volatile("s_waitcnt vmcnt(4)" ::: "memory"); }    \
    else              { asm volatile("s_waitcnt vmcnt(0)" ::: "memory"); }    \
    __builtin_amdgcn_s_barrier();                                             \
  } while (0)

  f32x4 acc[8][4];
#pragma unroll
  for (int i = 0; i < 8; ++i)
#pragma unroll
    for (int j = 0; j < 4; ++j)
      acc[i][j] = (f32x4){0.f, 0.f, 0.f, 0.f};

  STAGE(A0k0, aS0, aS1, 0, 0); STAGE(B0k0, bS0, bS1, 0, 0);
  STAGE(A0k1, aS0, aS1, 0, 1); STAGE(B0k1, bS0, bS1, 0, 1);
  STAGE(A1k0, aS0, aS1, 1, 0); STAGE(B1k0, bS0, bS1, 1, 0);
  asm volatile("s_waitcnt vmcnt(4)" ::: "memory");
  __builtin_amdgcn_s_barrier();

#pragma unroll 1
  for (int tt = 0; tt < NT; tt += 2) {
    ITER(tt,     A0k0, A0k1, B0k0, B0k1, A1k1, B1k1);
    ITER(tt + 1, A1k0, A1k1, B1k0, B1k1, A0k1, B0k1);
  }

#undef ITER
#undef MFMA_CLUSTER
#undef WAIT_LGKM
#undef STAGE

#pragma unroll
  for (int ni = 0; ni < 4; ++ni) {
    const int gc = n0 + wc * 64 + ni * 16 + fr;
    const float bval = bias[(size_t)e * NCOLS + gc];
#pragma unroll
    for (int MI = 0; MI < 8; ++MI) {
      const size_t orow = arow0 + (size_t)(wr * 128 + MI * 16 + rb);
#pragma unroll
      for (int j = 0; j < 4; ++j)
        OutF[(orow + j) * NCOLS + gc] = acc[MI][ni][j] + bval;
    }
  }
}

extern "C" void kernel_launch(void* const* d_in, const int* in_sizes, int n_in,
                              void* d_out, int out_size, void* d_ws, size_t ws_size,
                              hipStream_t stream) {
  const float* x  = (const float*)d_in[0];
  const float* w1 = (const float*)d_in[1];
  const float* b1 = (const float*)d_in[2];
  const float* w2 = (const float*)d_in[3];
  const float* b2 = (const float*)d_in[4];
  float* out = (float*)d_out;

  const size_t xN  = (size_t)B_ * E_ * N_ * D_;
  const size_t w1N = (size_t)E_ * D_ * H_;
  const size_t w2N = (size_t)E_ * H_ * D_;
  const size_t hN  = (size_t)B_ * E_ * N_ * H_;
  const size_t needed = (xN + w1N + w2N + hN) * 2;
  if (ws_size < needed) return;

  unsigned short* xb  = (unsigned short*)d_ws;
  unsigned short* w1t = xb + xN;   // [E][H][D] bf16
  unsigned short* w2t = w1t + w1N; // [E][D][H] bf16
  unsigned short* hb  = w2t + w2N; // [B][E][N][H] bf16

  // All conversions in one launch (w2t + w1t + x->bf16)
  fused_cvt<<<W2T_BLOCKS + W1T_BLOCKS + CVT_BLOCKS, 256, 0, stream>>>(
      w2, w1, x, w2t, w1t, xb, (int)(xN / 4));

  // GEMM1: 128² tiles, 32KB LDS -> 4096 blocks, 5 blocks/CU
  gemm_mlp1<<<E_ * 16 * 32, 256, 0, stream>>>(xb, w1t, b1, hb);
  // GEMM2: 256² tiles -> 256 blocks
  gemm_mlp2<<<E_ * 8 * (D_ / 256), 512, 0, stream>>>(hb, w2t, b2, out);
}

// Round 15
// 408.125 us; speedup vs baseline: 1.1338x; 1.0004x over previous
//
#include <hip/hip_runtime.h>
#include <stdint.h>

#define B_ 2
#define E_ 8
#define N_ 1024
#define D_ 1024
#define H_ 4096

typedef float f32x4 __attribute__((ext_vector_type(4)));
typedef __bf16 bf16x8 __attribute__((ext_vector_type(8)));
typedef __attribute__((address_space(3))) const unsigned short lds_cus;

__device__ __forceinline__ unsigned short f2bfu(float f) {
  __bf16 b = (__bf16)f;                      // native v_cvt, RNE
  return __builtin_bit_cast(unsigned short, b);
}

// tanh-form GELU, exp2-folded: g = x - x/(E+1), E = 2^(c1*x + c2*x^3)
__device__ __forceinline__ float gelu_fast(float x) {
  float u = x * x;
  float y = x * __builtin_fmaf(0.1029432f, u, 2.3022074f);
  float e = __builtin_exp2f(y);
  float r = __builtin_amdgcn_rcpf(e + 1.0f);
  return x - x * r;
}

__device__ __forceinline__ void gload_lds16(const unsigned short* g, unsigned short* l) {
  __builtin_amdgcn_global_load_lds(
      (__attribute__((address_space(1))) void*)g,
      (__attribute__((address_space(3))) void*)l,
      16, 0, 0);
}

__device__ __forceinline__ bf16x8 lds_read_b128(lds_cus* p) {
  bf16x8 r;
  asm volatile("ds_read_b128 %0, %1" : "=v"(r) : "v"(p));
  return r;
}

// ============================================================================
// Fused conversion kernel (R14, frozen)
// ============================================================================
#define W2T_BLOCKS ((H_ / 64) * (D_ / 64) * E_)   // 8192
#define W1T_BLOCKS ((D_ / 64) * (H_ / 64) * E_)   // 8192
#define CVT_BLOCKS 2048

__device__ __forceinline__ void transpose64(const float* __restrict__ src,
                                            unsigned short* __restrict__ dst,
                                            int R, int C, int jid, float (*tile)[65]) {
  const int tpe = (R >> 6) * (C >> 6);
  const int e = jid / tpe;
  const int rem = jid - e * tpe;
  const int ntc = C >> 6;
  const int tr = rem / ntc;
  const int tc = rem - tr * ntc;
  src += (size_t)e * R * C;
  dst += (size_t)e * R * C;
  const int r0 = tr << 6, c0 = tc << 6;

  const int tid = threadIdx.x;
  const int lr = tid >> 4;
  const int lc4 = (tid & 15) << 2;
#pragma unroll
  for (int i = 0; i < 4; ++i) {
    const float4 v = *(const float4*)&src[(size_t)(r0 + lr + i * 16) * C + c0 + lc4];
    tile[lr + i * 16][lc4 + 0] = v.x;
    tile[lr + i * 16][lc4 + 1] = v.y;
    tile[lr + i * 16][lc4 + 2] = v.z;
    tile[lr + i * 16][lc4 + 3] = v.w;
  }
  __syncthreads();
  const int wr4 = (tid & 15) << 2;
  const int wc = tid >> 4;
#pragma unroll
  for (int p = 0; p < 4; ++p) {
    const int c = wc + p * 16;
    ushort4 o;
    o.x = f2bfu(tile[wr4 + 0][c]);
    o.y = f2bfu(tile[wr4 + 1][c]);
    o.z = f2bfu(tile[wr4 + 2][c]);
    o.w = f2bfu(tile[wr4 + 3][c]);
    *(ushort4*)&dst[(size_t)(c0 + c) * R + r0 + wr4] = o;
  }
}

__global__ __launch_bounds__(256)
void fused_cvt(const float* __restrict__ w2, const float* __restrict__ w1,
               const float* __restrict__ x,
               unsigned short* __restrict__ w2t, unsigned short* __restrict__ w1t,
               unsigned short* __restrict__ xb, int n4) {
  __shared__ float tile[64][65];
  const int bid = blockIdx.x;
  if (bid < W2T_BLOCKS) {
    transpose64(w2, w2t, H_, D_, bid, tile);
  } else if (bid < W2T_BLOCKS + W1T_BLOCKS) {
    transpose64(w1, w1t, D_, H_, bid - W2T_BLOCKS, tile);
  } else {
    const int cb = bid - W2T_BLOCKS - W1T_BLOCKS;
    int idx = cb * 256 + threadIdx.x;
    const int stride = CVT_BLOCKS * 256;
    const float4* in4 = (const float4*)x;
    ushort4* out4 = (ushort4*)xb;
    for (int i = idx; i < n4; i += stride) {
      float4 f = in4[i];
      ushort4 o;
      o.x = f2bfu(f.x); o.y = f2bfu(f.y); o.z = f2bfu(f.z); o.w = f2bfu(f.w);
      out4[i] = o;
    }
  }
}

// ============================================================================
// GEMM1 (R13/R14 structure + R15 anti-lockstep stagger): 128x128, BK=64,
// 4 waves, single-buffered 32KB LDS -> 5 blocks/CU. The 5 co-resident blocks
// are de-phased by a one-time start delay of (flat%5)*~192 cyc so their
// staging round trips (~850 cyc, fully exposed when in lockstep) land inside
// the other blocks' compute windows. Blocks on one CU differ in flat by 8;
// {f,f+8,f+16,f+24,f+32} mod 5 hits all 5 phases.
// ============================================================================
__global__ __launch_bounds__(256, 4)
void gemm_mlp1(const unsigned short* __restrict__ A,     // xb  [16384][1024]
               const unsigned short* __restrict__ Bt,    // w1t [E][4096][1024]
               const float* __restrict__ bias,           // b1  [E][4096]
               unsigned short* __restrict__ Out) {       // hb  [16384][4096]
  constexpr int K = D_;
  constexpr int NCOLS = H_;
  constexpr int NT = K / 64;
  constexpr int MT = 16;
  constexpr int NTL = 32;

  __shared__ __align__(16) unsigned short Alds[8192];
  __shared__ __align__(16) unsigned short Blds[8192];

  const int nwg = gridDim.x;
  const int flat = blockIdx.x;

  // R15: anti-lockstep start ramp (block-uniform; ~192 cyc per step, 0..~768)
  const int ph = flat % 5;
#pragma unroll 1
  for (int i = 0; i < ph; ++i) __builtin_amdgcn_s_sleep(3);

  const int swz = (flat & 7) * (nwg >> 3) + (flat >> 3);
  const int e = swz / (MT * NTL);
  const int rem = swz - e * (MT * NTL);
  const int nt = rem >> 4;
  const int mt = rem & 15;

  const int m0 = mt * 128;
  const int b = m0 >> 10;
  const int nl = m0 & 1023;
  const size_t arow0 = (size_t)((b * E_ + e) * N_ + nl);
  const int n0 = nt * 128;

  const int tid = threadIdx.x;
  const int wid = tid >> 6;
  const int lane = tid & 63;
  const int wr = wid >> 1, wc = wid & 1;
  const int fr = lane & 15;
  const int kg = lane >> 4;

  const int lr = lane >> 3;
  const int sl = lane & 7;
  const unsigned short* aSrc[4];
  const unsigned short* bSrc[4];
  unsigned short* aDst[4];
  unsigned short* bDst[4];
#pragma unroll
  for (int j = 0; j < 4; ++j) {
    const int c = wid * 4 + j;
    const int grow = c * 8 + lr;
    const int f = (grow >> 1) & 7;
    const int ksl = (sl ^ f) << 3;
    aSrc[j] = A + (arow0 + grow) * K + ksl;
    bSrc[j] = Bt + ((size_t)e * NCOLS + n0 + grow) * K + ksl;
    aDst[j] = &Alds[c * 512];
    bDst[j] = &Blds[c * 512];
  }

  const int f_r = (fr >> 1) & 7;
  const int slot0 = kg ^ f_r;
  const int aRow = (wr * 64 + fr) * 64;
  const int bRow = (wc * 64 + fr) * 64;
  const int rb = kg * 4;

  f32x4 acc[4][4];
#pragma unroll
  for (int i = 0; i < 4; ++i)
#pragma unroll
    for (int j = 0; j < 4; ++j)
      acc[i][j] = (f32x4){0.f, 0.f, 0.f, 0.f};

#pragma unroll 1
  for (int t = 0; t < NT; ++t) {
    __syncthreads();
#pragma unroll
    for (int j = 0; j < 4; ++j) {
      gload_lds16(aSrc[j] + t * 64, aDst[j]);
      gload_lds16(bSrc[j] + t * 64, bDst[j]);
    }
    __syncthreads();
#pragma unroll
    for (int kh = 0; kh < 2; ++kh) {
      const int sx = (slot0 ^ (kh << 2)) << 3;
      bf16x8 av[4], bv[4];
#pragma unroll
      for (int i = 0; i < 4; ++i) {
        av[i] = *(const bf16x8*)&Alds[aRow + i * 1024 + sx];
        bv[i] = *(const bf16x8*)&Blds[bRow + i * 1024 + sx];
      }
      __builtin_amdgcn_s_setprio(1);
#pragma unroll
      for (int mi = 0; mi < 4; ++mi)
#pragma unroll
        for (int ni = 0; ni < 4; ++ni)
          acc[mi][ni] = __builtin_amdgcn_mfma_f32_16x16x32_bf16(av[mi], bv[ni], acc[mi][ni], 0, 0, 0);
      __builtin_amdgcn_s_setprio(0);
    }
  }

  float bval[4];
#pragma unroll
  for (int ni = 0; ni < 4; ++ni)
    bval[ni] = bias[(size_t)e * NCOLS + n0 + wc * 64 + ni * 16 + fr];
  const size_t gcb = (size_t)n0 + wc * 64 + fr;
#pragma unroll
  for (int mi = 0; mi < 4; ++mi) {
#pragma unroll
    for (int j = 0; j < 4; ++j) {
      const size_t orow = arow0 + (size_t)(wr * 64 + mi * 16 + rb + j);
      unsigned short* rp = Out + orow * NCOLS + gcb;
#pragma unroll
      for (int ni = 0; ni < 4; ++ni)
        rp[ni * 16] = f2bfu(gelu_fast(acc[mi][ni][j] + bval[ni]));
    }
  }
}

// ============================================================================
// GEMM2 (R4-proven structure, frozen): 256x256, BK=64, 8 waves, 4-phase/K-tile,
// named 128KB LDS, counted vmcnt(4), plain fp32 stores.
// ============================================================================
__global__ __launch_bounds__(512, 2)
void gemm_mlp2(const unsigned short* __restrict__ A,     // hb  [16384][4096]
               const unsigned short* __restrict__ Bt,    // w2t [E][1024][4096]
               const float* __restrict__ bias,           // b2  [E][1024]
               float* __restrict__ OutF) {               // out [16384][1024]
  constexpr int K = H_;
  constexpr int NCOLS = D_;
  constexpr int NT = K / 64;
  constexpr int MT = 8;
  constexpr int NTL = 4;

  __shared__ __align__(16) unsigned short A0k0[8192], A0k1[8192], B0k0[8192], B0k1[8192];
  __shared__ __align__(16) unsigned short A1k0[8192], A1k1[8192], B1k0[8192], B1k1[8192];

  const int nwg = gridDim.x;
  const int flat = blockIdx.x;
  const int swz = (flat & 7) * (nwg >> 3) + (flat >> 3);
  const int e = swz / (MT * NTL);
  const int rem = swz - e * (MT * NTL);
  const int nt = rem / MT;
  const int mt = rem - nt * MT;

  const int m0 = mt * 256;
  const int b = m0 >> 10;
  const int nl = m0 & 1023;
  const size_t arow0 = (size_t)((b * E_ + e) * N_ + nl);
  const int n0 = nt * 256;

  const unsigned short* Ab = A + arow0 * K;
  const unsigned short* Bb = Bt + ((size_t)e * NCOLS + n0) * K;

  const int tid = threadIdx.x;
  const int w = tid >> 6;
  const int lane = tid & 63;
  const int wr = w >> 2;
  const int wc = w & 3;
  const int fr = lane & 15;
  const int kg = lane >> 4;
  const int sxor = kg ^ ((lane >> 1) & 3);

  const int scol = (((lane & 3) ^ ((lane >> 3) & 3)) << 3);
  const int srow0 = w * 32 + (lane >> 2);
  const int srow1 = srow0 + 16;
  const unsigned short* aS0 = Ab + (size_t)srow0 * K + scol;
  const unsigned short* aS1 = Ab + (size_t)srow1 * K + scol;
  const unsigned short* bS0 = Bb + (size_t)srow0 * K + scol;
  const unsigned short* bS1 = Bb + (size_t)srow1 * K + scol;

  const int aBase = (wr * 128 + fr) * 32 + sxor * 8;
  const int bBase = (wc * 64 + fr) * 32 + sxor * 8;
  const int rb = kg * 4;

#define STAGE(ARR, S0_, S1_, t, kh) do {                           \
    const size_t ko_ = (size_t)(t) * 64 + (kh) * 32;               \
    gload_lds16(S0_ + ko_, &ARR[w * 1024]);                        \
    gload_lds16(S1_ + ko_, &ARR[w * 1024 + 512]);                  \
  } while (0)

#define WAIT_LGKM() do {                                                      \
    asm volatile("s_waitcnt lgkmcnt(0)");                                     \
    __builtin_amdgcn_sched_barrier(0);                                        \
  } while (0)

#define MFMA_CLUSTER(ROFF)                                                    \
    __builtin_amdgcn_s_setprio(1);                                            \
    _Pragma("unroll")                                                         \
    for (int mi = 0; mi < 4; ++mi)                                            \
      _Pragma("unroll")                                                       \
      for (int ni = 0; ni < 4; ++ni)                                          \
        acc[(ROFF) + mi][ni] =                                                \
            __builtin_amdgcn_mfma_f32_16x16x32_bf16(av[mi], bv[ni],           \
                                                    acc[(ROFF) + mi][ni], 0, 0, 0); \
    __builtin_amdgcn_s_setprio(0);

#define ITER(t, CA0, CA1, CB0, CB1, NA1, NB1) do {                            \
    bf16x8 av[4], bv[4];                                                      \
    _Pragma("unroll")                                                         \
    for (int i = 0; i < 4; ++i) {                                             \
      av[i] = lds_read_b128((lds_cus*)&CA0[aBase + i * 512]);                 \
      bv[i] = lds_read_b128((lds_cus*)&CB0[bBase + i * 512]);                 \
    }                                                                         \
    if ((t) + 1 < NT) STAGE(NA1, aS0, aS1, (t) + 1, 1);                       \
    __builtin_amdgcn_s_barrier();                                             \
    WAIT_LGKM();                                                              \
    MFMA_CLUSTER(0)                                                           \
    __builtin_amdgcn_s_barrier();                                             \
    _Pragma("unroll")                                                         \
    for (int i = 0; i < 4; ++i)                                               \
      av[i] = lds_read_b128((lds_cus*)&CA0[aBase + 2048 + i * 512]);          \
    if ((t) + 1 < NT) STAGE(NB1, bS0, bS1, (t) + 1, 1);                       \
    __builtin_amdgcn_s_barrier();                                             \
    WAIT_LGKM();                                                              \
    MFMA_CLUSTER(4)                                                           \
    __builtin_amdgcn_s_barrier();                                             \
    _Pragma("unroll")                                                         \
    for (int i = 0; i < 4; ++i) {                                             \
      av[i] = lds_read_b128((lds_cus*)&CA1[aBase + i * 512]);                 \
      bv[i] = lds_read_b128((lds_cus*)&CB1[bBase + i * 512]);                 \
    }                                                                         \
    if ((t) + 2 < NT) STAGE(CA0, aS0, aS1, (t) + 2, 0);                       \
    __builtin_amdgcn_s_barrier();                                             \
    WAIT_LGKM();                                                              \
    MFMA_CLUSTER(0)                                                           \
    __builtin_amdgcn_s_barrier();                                             \
    _Pragma("unroll")                                                         \
    for (int i = 0; i < 4; ++i)                                               \
      av[i] = lds_read_b128((lds_cus*)&CA1[aBase + 2048 + i * 512]);          \
    if ((t) + 2 < NT) STAGE(CB0, bS0, bS1, (t) + 2, 0);                       \
    __builtin_amdgcn_s_barrier();                                             \
    WAIT_LGKM();                                                              \
    MFMA_CLUSTER(4)                                                           \
    if ((t) + 2 < NT) { asm volatile("s_waitcnt vmcnt(4)" ::: "memory"); }    \
    else              { asm volatile("s_waitcnt vmcnt(0)" ::: "memory"); }    \
    __builtin_amdgcn_s_barrier();                                             \
  } while (0)

  f32x4 acc[8][4];
#pragma unroll
  for (int i = 0; i < 8; ++i)
#pragma unroll
    for (int j = 0; j < 4; ++j)
      acc[i][j] = (f32x4){0.f, 0.f, 0.f, 0.f};

  STAGE(A0k0, aS0, aS1, 0, 0); STAGE(B0k0, bS0, bS1, 0, 0);
  STAGE(A0k1, aS0, aS1, 0, 1); STAGE(B0k1, bS0, bS1, 0, 1);
  STAGE(A1k0, aS0, aS1, 1, 0); STAGE(B1k0, bS0, bS1, 1, 0);
  asm volatile("s_waitcnt vmcnt(4)" ::: "memory");
  __builtin_amdgcn_s_barrier();

#pragma unroll 1
  for (int tt = 0; tt < NT; tt += 2) {
    ITER(tt,     A0k0, A0k1, B0k0, B0k1, A1k1, B1k1);
    ITER(tt + 1, A1k0, A1k1, B1k0, B1k1, A0k1, B0k1);
  }

#undef ITER
#undef MFMA_CLUSTER
#undef WAIT_LGKM
#undef STAGE

#pragma unroll
  for (int ni = 0; ni < 4; ++ni) {
    const int gc = n0 + wc * 64 + ni * 16 + fr;
    const float bval = bias[(size_t)e * NCOLS + gc];
#pragma unroll
    for (int MI = 0; MI < 8; ++MI) {
      const size_t orow = arow0 + (size_t)(wr * 128 + MI * 16 + rb);
#pragma unroll
      for (int j = 0; j < 4; ++j)
        OutF[(orow + j) * NCOLS + gc] = acc[MI][ni][j] + bval;
    }
  }
}

extern "C" void kernel_launch(void* const* d_in, const int* in_sizes, int n_in,
                              void* d_out, int out_size, void* d_ws, size_t ws_size,
                              hipStream_t stream) {
  const float* x  = (const float*)d_in[0];
  const float* w1 = (const float*)d_in[1];
  const float* b1 = (const float*)d_in[2];
  const float* w2 = (const float*)d_in[3];
  const float* b2 = (const float*)d_in[4];
  float* out = (float*)d_out;

  const size_t xN  = (size_t)B_ * E_ * N_ * D_;
  const size_t w1N = (size_t)E_ * D_ * H_;
  const size_t w2N = (size_t)E_ * H_ * D_;
  const size_t hN  = (size_t)B_ * E_ * N_ * H_;
  const size_t needed = (xN + w1N + w2N + hN) * 2;
  if (ws_size < needed) return;

  unsigned short* xb  = (unsigned short*)d_ws;
  unsigned short* w1t = xb + xN;   // [E][H][D] bf16
  unsigned short* w2t = w1t + w1N; // [E][D][H] bf16
  unsigned short* hb  = w2t + w2N; // [B][E][N][H] bf16

  fused_cvt<<<W2T_BLOCKS + W1T_BLOCKS + CVT_BLOCKS, 256, 0, stream>>>(
      w2, w1, x, w2t, w1t, xb, (int)(xN / 4));

  // GEMM1: 128² tiles, 32KB LDS -> 4096 blocks, 5 blocks/CU, de-phased
  gemm_mlp1<<<E_ * 16 * 32, 256, 0, stream>>>(xb, w1t, b1, hb);
  // GEMM2: 256² tiles -> 256 blocks
  gemm_mlp2<<<E_ * 8 * (D_ / 256), 512, 0, stream>>>(hb, w2t, b2, out);
}

// Round 16
// 406.253 us; speedup vs baseline: 1.1390x; 1.0046x over previous
//
#include <hip/hip_runtime.h>
#include <stdint.h>

#define B_ 2
#define E_ 8
#define N_ 1024
#define D_ 1024
#define H_ 4096

typedef float f32x4 __attribute__((ext_vector_type(4)));
typedef __bf16 bf16x8 __attribute__((ext_vector_type(8)));
typedef __attribute__((address_space(3))) const unsigned short lds_cus;

__device__ __forceinline__ unsigned short f2bfu(float f) {
  __bf16 b = (__bf16)f;                      // native v_cvt, RNE
  return __builtin_bit_cast(unsigned short, b);
}

// tanh-form GELU, exp2-folded: g = x - x/(E+1), E = 2^(c1*x + c2*x^3)
__device__ __forceinline__ float gelu_fast(float x) {
  float u = x * x;
  float y = x * __builtin_fmaf(0.1029432f, u, 2.3022074f);
  float e = __builtin_exp2f(y);
  float r = __builtin_amdgcn_rcpf(e + 1.0f);
  return x - x * r;
}

__device__ __forceinline__ void gload_lds16(const unsigned short* g, unsigned short* l) {
  __builtin_amdgcn_global_load_lds(
      (__attribute__((address_space(1))) void*)g,
      (__attribute__((address_space(3))) void*)l,
      16, 0, 0);
}

__device__ __forceinline__ bf16x8 lds_read_b128(lds_cus* p) {
  bf16x8 r;
  asm volatile("ds_read_b128 %0, %1" : "=v"(r) : "v"(p));
  return r;
}

// ============================================================================
// Fused conversion kernel (R14, frozen)
// ============================================================================
#define W2T_BLOCKS ((H_ / 64) * (D_ / 64) * E_)   // 8192
#define W1T_BLOCKS ((D_ / 64) * (H_ / 64) * E_)   // 8192
#define CVT_BLOCKS 2048

__device__ __forceinline__ void transpose64(const float* __restrict__ src,
                                            unsigned short* __restrict__ dst,
                                            int R, int C, int jid, float (*tile)[65]) {
  const int tpe = (R >> 6) * (C >> 6);
  const int e = jid / tpe;
  const int rem = jid - e * tpe;
  const int ntc = C >> 6;
  const int tr = rem / ntc;
  const int tc = rem - tr * ntc;
  src += (size_t)e * R * C;
  dst += (size_t)e * R * C;
  const int r0 = tr << 6, c0 = tc << 6;

  const int tid = threadIdx.x;
  const int lr = tid >> 4;
  const int lc4 = (tid & 15) << 2;
#pragma unroll
  for (int i = 0; i < 4; ++i) {
    const float4 v = *(const float4*)&src[(size_t)(r0 + lr + i * 16) * C + c0 + lc4];
    tile[lr + i * 16][lc4 + 0] = v.x;
    tile[lr + i * 16][lc4 + 1] = v.y;
    tile[lr + i * 16][lc4 + 2] = v.z;
    tile[lr + i * 16][lc4 + 3] = v.w;
  }
  __syncthreads();
  const int wr4 = (tid & 15) << 2;
  const int wc = tid >> 4;
#pragma unroll
  for (int p = 0; p < 4; ++p) {
    const int c = wc + p * 16;
    ushort4 o;
    o.x = f2bfu(tile[wr4 + 0][c]);
    o.y = f2bfu(tile[wr4 + 1][c]);
    o.z = f2bfu(tile[wr4 + 2][c]);
    o.w = f2bfu(tile[wr4 + 3][c]);
    *(ushort4*)&dst[(size_t)(c0 + c) * R + r0 + wr4] = o;
  }
}

__global__ __launch_bounds__(256)
void fused_cvt(const float* __restrict__ w2, const float* __restrict__ w1,
               const float* __restrict__ x,
               unsigned short* __restrict__ w2t, unsigned short* __restrict__ w1t,
               unsigned short* __restrict__ xb, int n4) {
  __shared__ float tile[64][65];
  const int bid = blockIdx.x;
  if (bid < W2T_BLOCKS) {
    transpose64(w2, w2t, H_, D_, bid, tile);
  } else if (bid < W2T_BLOCKS + W1T_BLOCKS) {
    transpose64(w1, w1t, D_, H_, bid - W2T_BLOCKS, tile);
  } else {
    const int cb = bid - W2T_BLOCKS - W1T_BLOCKS;
    int idx = cb * 256 + threadIdx.x;
    const int stride = CVT_BLOCKS * 256;
    const float4* in4 = (const float4*)x;
    ushort4* out4 = (ushort4*)xb;
    for (int i = idx; i < n4; i += stride) {
      float4 f = in4[i];
      ushort4 o;
      o.x = f2bfu(f.x); o.y = f2bfu(f.y); o.z = f2bfu(f.z); o.w = f2bfu(f.w);
      out4[i] = o;
    }
  }
}

// ============================================================================
// GEMM1 (R16): 256x128 block tile, 8 waves (4m x 2n) of 64x64, BK=64,
// single-buffered 48KB LDS (A 32KB + B 16KB). Same R13 drain-0 loop, same
// 8-slot XOR swizzle, same per-wave register footprint (64 VGPR + 64 AGPR).
// vs R13's 128x128: block-K-tiles/CU halve (stage-exposure total halves),
// staged traffic -25%, LDS-read traffic unchanged, wave occupancy equal.
// ============================================================================
__global__ __launch_bounds__(512, 2)
void gemm_mlp1(const unsigned short* __restrict__ A,     // xb  [16384][1024]
               const unsigned short* __restrict__ Bt,    // w1t [E][4096][1024]
               const float* __restrict__ bias,           // b1  [E][4096]
               unsigned short* __restrict__ Out) {       // hb  [16384][4096]
  constexpr int K = D_;        // 1024
  constexpr int NCOLS = H_;    // 4096
  constexpr int NT = K / 64;   // 16
  constexpr int MT = 8;        // 2048/256 m-tiles per expert
  constexpr int NTL = 32;      // 4096/128 n-tiles per expert

  __shared__ __align__(16) unsigned short Alds[16384];   // [256 rows][8 slots of 8]
  __shared__ __align__(16) unsigned short Blds[8192];    // [128 rows][8 slots of 8]

  const int nwg = gridDim.x;               // 2048, %8==0
  const int flat = blockIdx.x;
  const int swz = (flat & 7) * (nwg >> 3) + (flat >> 3);
  const int e = swz / (MT * NTL);
  const int rem = swz - e * (MT * NTL);
  const int nt = rem >> 3;                 // 0..31
  const int mt = rem & 7;                  // 0..7

  const int m0 = mt * 256;
  const int b = m0 >> 10;
  const int nl = m0 & 1023;
  const size_t arow0 = (size_t)((b * E_ + e) * N_ + nl);
  const int n0 = nt * 128;

  const int tid = threadIdx.x;
  const int wid = tid >> 6;                // 0..7
  const int lane = tid & 63;
  const int wr = wid >> 1;                 // 0..3 (64-row quarter)
  const int wc = wid & 1;                  // 0..1 (64-col half)
  const int fr = lane & 15;
  const int kg = lane >> 4;

  // ---- staging: A 32 chunks (4/wave), B 16 chunks (2/wave); chunk = 8 rows,
  // lane: row lr=lane>>3, 16B slot sl=lane&7; source k pre-swizzled so linear
  // LDS dest ends up physically swizzled (rule #21).
  const int lr = lane >> 3;
  const int sl = lane & 7;
  const unsigned short* aSrc[4];
  const unsigned short* bSrc[2];
  unsigned short* aDst[4];
  unsigned short* bDst[2];
#pragma unroll
  for (int j = 0; j < 4; ++j) {
    const int c = wid * 4 + j;             // 0..31
    const int grow = c * 8 + lr;           // 0..255
    const int f = (grow >> 1) & 7;
    const int ksl = (sl ^ f) << 3;
    aSrc[j] = A + (arow0 + grow) * K + ksl;
    aDst[j] = &Alds[c * 512];
  }
#pragma unroll
  for (int j = 0; j < 2; ++j) {
    const int c = wid * 2 + j;             // 0..15
    const int grow = c * 8 + lr;           // 0..127
    const int f = (grow >> 1) & 7;
    const int ksl = (sl ^ f) << 3;
    bSrc[j] = Bt + ((size_t)e * NCOLS + n0 + grow) * K + ksl;
    bDst[j] = &Blds[c * 512];
  }

  // ---- fragment-read addressing (row bases multiples of 16 => the row-XOR
  // factor reduces to (fr>>1)&7, same as R13) ----
  const int f_r = (fr >> 1) & 7;
  const int slot0 = kg ^ f_r;
  const int aRow = (wr * 64 + fr) * 64;
  const int bRow = (wc * 64 + fr) * 64;
  const int rb = kg * 4;

  f32x4 acc[4][4];
#pragma unroll
  for (int i = 0; i < 4; ++i)
#pragma unroll
    for (int j = 0; j < 4; ++j)
      acc[i][j] = (f32x4){0.f, 0.f, 0.f, 0.f};

#pragma unroll 1
  for (int t = 0; t < NT; ++t) {
    __syncthreads();  // previous tile's reads done before LDS overwrite
#pragma unroll
    for (int j = 0; j < 4; ++j)
      gload_lds16(aSrc[j] + t * 64, aDst[j]);
#pragma unroll
    for (int j = 0; j < 2; ++j)
      gload_lds16(bSrc[j] + t * 64, bDst[j]);
    __syncthreads();  // compiler drains vmcnt(0): staged tile visible
#pragma unroll
    for (int kh = 0; kh < 2; ++kh) {
      const int sx = (slot0 ^ (kh << 2)) << 3;
      bf16x8 av[4], bv[4];
#pragma unroll
      for (int i = 0; i < 4; ++i) {
        av[i] = *(const bf16x8*)&Alds[aRow + i * 1024 + sx];
        bv[i] = *(const bf16x8*)&Blds[bRow + i * 1024 + sx];
      }
      __builtin_amdgcn_s_setprio(1);
#pragma unroll
      for (int mi = 0; mi < 4; ++mi)
#pragma unroll
        for (int ni = 0; ni < 4; ++ni)
          acc[mi][ni] = __builtin_amdgcn_mfma_f32_16x16x32_bf16(av[mi], bv[ni], acc[mi][ni], 0, 0, 0);
      __builtin_amdgcn_s_setprio(0);
    }
  }

  // epilogue: C/D layout col=lane&15, row=(lane>>4)*4+j; ni-inner plain stores
  float bval[4];
#pragma unroll
  for (int ni = 0; ni < 4; ++ni)
    bval[ni] = bias[(size_t)e * NCOLS + n0 + wc * 64 + ni * 16 + fr];
  const size_t gcb = (size_t)n0 + wc * 64 + fr;
#pragma unroll
  for (int mi = 0; mi < 4; ++mi) {
#pragma unroll
    for (int j = 0; j < 4; ++j) {
      const size_t orow = arow0 + (size_t)(wr * 64 + mi * 16 + rb + j);
      unsigned short* rp = Out + orow * NCOLS + gcb;
#pragma unroll
      for (int ni = 0; ni < 4; ++ni)
        rp[ni * 16] = f2bfu(gelu_fast(acc[mi][ni][j] + bval[ni]));
    }
  }
}

// ============================================================================
// GEMM2 (R4-proven structure, frozen): 256x256, BK=64, 8 waves, 4-phase/K-tile,
// named 128KB LDS, counted vmcnt(4), plain fp32 stores.
// ============================================================================
__global__ __launch_bounds__(512, 2)
void gemm_mlp2(const unsigned short* __restrict__ A,     // hb  [16384][4096]
               const unsigned short* __restrict__ Bt,    // w2t [E][1024][4096]
               const float* __restrict__ bias,           // b2  [E][1024]
               float* __restrict__ OutF) {               // out [16384][1024]
  constexpr int K = H_;
  constexpr int NCOLS = D_;
  constexpr int NT = K / 64;
  constexpr int MT = 8;
  constexpr int NTL = 4;

  __shared__ __align__(16) unsigned short A0k0[8192], A0k1[8192], B0k0[8192], B0k1[8192];
  __shared__ __align__(16) unsigned short A1k0[8192], A1k1[8192], B1k0[8192], B1k1[8192];

  const int nwg = gridDim.x;
  const int flat = blockIdx.x;
  const int swz = (flat & 7) * (nwg >> 3) + (flat >> 3);
  const int e = swz / (MT * NTL);
  const int rem = swz - e * (MT * NTL);
  const int nt = rem / MT;
  const int mt = rem - nt * MT;

  const int m0 = mt * 256;
  const int b = m0 >> 10;
  const int nl = m0 & 1023;
  const size_t arow0 = (size_t)((b * E_ + e) * N_ + nl);
  const int n0 = nt * 256;

  const unsigned short* Ab = A + arow0 * K;
  const unsigned short* Bb = Bt + ((size_t)e * NCOLS + n0) * K;

  const int tid = threadIdx.x;
  const int w = tid >> 6;
  const int lane = tid & 63;
  const int wr = w >> 2;
  const int wc = w & 3;
  const int fr = lane & 15;
  const int kg = lane >> 4;
  const int sxor = kg ^ ((lane >> 1) & 3);

  const int scol = (((lane & 3) ^ ((lane >> 3) & 3)) << 3);
  const int srow0 = w * 32 + (lane >> 2);
  const int srow1 = srow0 + 16;
  const unsigned short* aS0 = Ab + (size_t)srow0 * K + scol;
  const unsigned short* aS1 = Ab + (size_t)srow1 * K + scol;
  const unsigned short* bS0 = Bb + (size_t)srow0 * K + scol;
  const unsigned short* bS1 = Bb + (size_t)srow1 * K + scol;

  const int aBase = (wr * 128 + fr) * 32 + sxor * 8;
  const int bBase = (wc * 64 + fr) * 32 + sxor * 8;
  const int rb = kg * 4;

#define STAGE(ARR, S0_, S1_, t, kh) do {                           \
    const size_t ko_ = (size_t)(t) * 64 + (kh) * 32;               \
    gload_lds16(S0_ + ko_, &ARR[w * 1024]);                        \
    gload_lds16(S1_ + ko_, &ARR[w * 1024 + 512]);                  \
  } while (0)

#define WAIT_LGKM() do {                                                      \
    asm volatile("s_waitcnt lgkmcnt(0)");                                     \
    __builtin_amdgcn_sched_barrier(0);                                        \
  } while (0)

#define MFMA_CLUSTER(ROFF)                                                    \
    __builtin_amdgcn_s_setprio(1);                                            \
    _Pragma("unroll")                                                         \
    for (int mi = 0; mi < 4; ++mi)                                            \
      _Pragma("unroll")                                                       \
      for (int ni = 0; ni < 4; ++ni)                                          \
        acc[(ROFF) + mi][ni] =                                                \
            __builtin_amdgcn_mfma_f32_16x16x32_bf16(av[mi], bv[ni],           \
                                                    acc[(ROFF) + mi][ni], 0, 0, 0); \
    __builtin_amdgcn_s_setprio(0);

#define ITER(t, CA0, CA1, CB0, CB1, NA1, NB1) do {                            \
    bf16x8 av[4], bv[4];                                                      \
    _Pragma("unroll")                                                         \
    for (int i = 0; i < 4; ++i) {                                             \
      av[i] = lds_read_b128((lds_cus*)&CA0[aBase + i * 512]);                 \
      bv[i] = lds_read_b128((lds_cus*)&CB0[bBase + i * 512]);                 \
    }                                                                         \
    if ((t) + 1 < NT) STAGE(NA1, aS0, aS1, (t) + 1, 1);                       \
    __builtin_amdgcn_s_barrier();                                             \
    WAIT_LGKM();                                                              \
    MFMA_CLUSTER(0)                                                           \
    __builtin_amdgcn_s_barrier();                                             \
    _Pragma("unroll")                                                         \
    for (int i = 0; i < 4; ++i)                                               \
      av[i] = lds_read_b128((lds_cus*)&CA0[aBase + 2048 + i * 512]);          \
    if ((t) + 1 < NT) STAGE(NB1, bS0, bS1, (t) + 1, 1);                       \
    __builtin_amdgcn_s_barrier();                                             \
    WAIT_LGKM();                                                              \
    MFMA_CLUSTER(4)                                                           \
    __builtin_amdgcn_s_barrier();                                             \
    _Pragma("unroll")                                                         \
    for (int i = 0; i < 4; ++i) {                                             \
      av[i] = lds_read_b128((lds_cus*)&CA1[aBase + i * 512]);                 \
      bv[i] = lds_read_b128((lds_cus*)&CB1[bBase + i * 512]);                 \
    }                                                                         \
    if ((t) + 2 < NT) STAGE(CA0, aS0, aS1, (t) + 2, 0);                       \
    __builtin_amdgcn_s_barrier();                                             \
    WAIT_LGKM();                                                              \
    MFMA_CLUSTER(0)                                                           \
    __builtin_amdgcn_s_barrier();                                             \
    _Pragma("unroll")                                                         \
    for (int i = 0; i < 4; ++i)                                               \
      av[i] = lds_read_b128((lds_cus*)&CA1[aBase + 2048 + i * 512]);          \
    if ((t) + 2 < NT) STAGE(CB0, bS0, bS1, (t) + 2, 0);                       \
    __builtin_amdgcn_s_barrier();                                             \
    WAIT_LGKM();                                                              \
    MFMA_CLUSTER(4)                                                           \
    if ((t) + 2 < NT) { asm volatile("s_waitcnt vmcnt(4)" ::: "memory"); }    \
    else              { asm volatile("s_waitcnt vmcnt(0)" ::: "memory"); }    \
    __builtin_amdgcn_s_barrier();                                             \
  } while (0)

  f32x4 acc[8][4];
#pragma unroll
  for (int i = 0; i < 8; ++i)
#pragma unroll
    for (int j = 0; j < 4; ++j)
      acc[i][j] = (f32x4){0.f, 0.f, 0.f, 0.f};

  STAGE(A0k0, aS0, aS1, 0, 0); STAGE(B0k0, bS0, bS1, 0, 0);
  STAGE(A0k1, aS0, aS1, 0, 1); STAGE(B0k1, bS0, bS1, 0, 1);
  STAGE(A1k0, aS0, aS1, 1, 0); STAGE(B1k0, bS0, bS1, 1, 0);
  asm volatile("s_waitcnt vmcnt(4)" ::: "memory");
  __builtin_amdgcn_s_barrier();

#pragma unroll 1
  for (int tt = 0; tt < NT; tt += 2) {
    ITER(tt,     A0k0, A0k1, B0k0, B0k1, A1k1, B1k1);
    ITER(tt + 1, A1k0, A1k1, B1k0, B1k1, A0k1, B0k1);
  }

#undef ITER
#undef MFMA_CLUSTER
#undef WAIT_LGKM
#undef STAGE

#pragma unroll
  for (int ni = 0; ni < 4; ++ni) {
    const int gc = n0 + wc * 64 + ni * 16 + fr;
    const float bval = bias[(size_t)e * NCOLS + gc];
#pragma unroll
    for (int MI = 0; MI < 8; ++MI) {
      const size_t orow = arow0 + (size_t)(wr * 128 + MI * 16 + rb);
#pragma unroll
      for (int j = 0; j < 4; ++j)
        OutF[(orow + j) * NCOLS + gc] = acc[MI][ni][j] + bval;
    }
  }
}

extern "C" void kernel_launch(void* const* d_in, const int* in_sizes, int n_in,
                              void* d_out, int out_size, void* d_ws, size_t ws_size,
                              hipStream_t stream) {
  const float* x  = (const float*)d_in[0];
  const float* w1 = (const float*)d_in[1];
  const float* b1 = (const float*)d_in[2];
  const float* w2 = (const float*)d_in[3];
  const float* b2 = (const float*)d_in[4];
  float* out = (float*)d_out;

  const size_t xN  = (size_t)B_ * E_ * N_ * D_;
  const size_t w1N = (size_t)E_ * D_ * H_;
  const size_t w2N = (size_t)E_ * H_ * D_;
  const size_t hN  = (size_t)B_ * E_ * N_ * H_;
  const size_t needed = (xN + w1N + w2N + hN) * 2;
  if (ws_size < needed) return;

  unsigned short* xb  = (unsigned short*)d_ws;
  unsigned short* w1t = xb + xN;   // [E][H][D] bf16
  unsigned short* w2t = w1t + w1N; // [E][D][H] bf16
  unsigned short* hb  = w2t + w2N; // [B][E][N][H] bf16

  fused_cvt<<<W2T_BLOCKS + W1T_BLOCKS + CVT_BLOCKS, 256, 0, stream>>>(
      w2, w1, x, w2t, w1t, xb, (int)(xN / 4));

  // GEMM1: 256x128 tiles, 48KB LDS -> 8e x 8mt x 32nt = 2048 blocks
  gemm_mlp1<<<E_ * 8 * 32, 512, 0, stream>>>(xb, w1t, b1, hb);
  // GEMM2: 256² tiles -> 256 blocks
  gemm_mlp2<<<E_ * 8 * (D_ / 256), 512, 0, stream>>>(hb, w2t, b2, out);
}